// Round 1
// baseline (2301.921 us; speedup 1.0000x reference)
//
#include <hip/hip_runtime.h>

#define DD 256

// ---------------- QKV projection GEMM: Q/K/V = x @ W^T + b ----------------
// grid: (rows/64, 4), block 256. 64x64 tile, 4x4 per thread, 3 weight mats.
__global__ __launch_bounds__(256)
void qkv_gemm(const float* __restrict__ x,
              const float* __restrict__ wq, const float* __restrict__ bq,
              const float* __restrict__ wk, const float* __restrict__ bk,
              const float* __restrict__ wv, const float* __restrict__ bv,
              float* __restrict__ Q, float* __restrict__ Ko, float* __restrict__ V)
{
    __shared__ __align__(16) float xs[16][64];
    __shared__ __align__(16) float ws[3][16][64];
    const int tid = threadIdx.x;
    const int tx = tid & 15, ty = tid >> 4;
    const long row0 = (long)blockIdx.x * 64;
    const int c0 = blockIdx.y * 64;
    const int lrow = tid >> 2;           // 0..63
    const int lk4 = (tid & 3) << 2;      // 0,4,8,12
    const float* wm[3] = {wq, wk, wv};
    float acc[3][4][4] = {};

    for (int kk = 0; kk < DD; kk += 16) {
        float4 xv = *(const float4*)&x[(row0 + lrow) * DD + kk + lk4];
        xs[lk4+0][lrow] = xv.x; xs[lk4+1][lrow] = xv.y;
        xs[lk4+2][lrow] = xv.z; xs[lk4+3][lrow] = xv.w;
        #pragma unroll
        for (int j = 0; j < 3; ++j) {
            float4 wv4 = *(const float4*)&wm[j][(long)(c0 + lrow) * DD + kk + lk4];
            ws[j][lk4+0][lrow] = wv4.x; ws[j][lk4+1][lrow] = wv4.y;
            ws[j][lk4+2][lrow] = wv4.z; ws[j][lk4+3][lrow] = wv4.w;
        }
        __syncthreads();
        #pragma unroll
        for (int k = 0; k < 16; ++k) {
            float4 a4 = *(const float4*)&xs[k][ty << 2];
            float4 b0 = *(const float4*)&ws[0][k][tx << 2];
            float4 b1 = *(const float4*)&ws[1][k][tx << 2];
            float4 b2 = *(const float4*)&ws[2][k][tx << 2];
            float av[4] = {a4.x, a4.y, a4.z, a4.w};
            float bv0[4] = {b0.x, b0.y, b0.z, b0.w};
            float bv1[4] = {b1.x, b1.y, b1.z, b1.w};
            float bv2[4] = {b2.x, b2.y, b2.z, b2.w};
            #pragma unroll
            for (int r = 0; r < 4; ++r)
                #pragma unroll
                for (int c = 0; c < 4; ++c) {
                    acc[0][r][c] += av[r] * bv0[c];
                    acc[1][r][c] += av[r] * bv1[c];
                    acc[2][r][c] += av[r] * bv2[c];
                }
        }
        __syncthreads();
    }
    float4 bq4 = *(const float4*)&bq[c0 + (tx << 2)];
    float4 bk4 = *(const float4*)&bk[c0 + (tx << 2)];
    float4 bv4 = *(const float4*)&bv[c0 + (tx << 2)];
    #pragma unroll
    for (int r = 0; r < 4; ++r) {
        long orow = (row0 + (ty << 2) + r) * DD + c0 + (tx << 2);
        *(float4*)&Q [orow] = make_float4(acc[0][r][0]+bq4.x, acc[0][r][1]+bq4.y, acc[0][r][2]+bq4.z, acc[0][r][3]+bq4.w);
        *(float4*)&Ko[orow] = make_float4(acc[1][r][0]+bk4.x, acc[1][r][1]+bk4.y, acc[1][r][2]+bk4.z, acc[1][r][3]+bk4.w);
        *(float4*)&V [orow] = make_float4(acc[2][r][0]+bv4.x, acc[2][r][1]+bv4.y, acc[2][r][2]+bv4.z, acc[2][r][3]+bv4.w);
    }
}

// ---------------- Pool gate GEMM: P = g * tanh(xW^T+bW) * sigmoid(xU^T+bU) ----------------
__global__ __launch_bounds__(256)
void pool_gemm(const float* __restrict__ x,
               const float* __restrict__ W, const float* __restrict__ bW,
               const float* __restrict__ U, const float* __restrict__ bU,
               const float* __restrict__ g, float* __restrict__ P)
{
    __shared__ __align__(16) float xs[16][64];
    __shared__ __align__(16) float ws[2][16][64];
    const int tid = threadIdx.x;
    const int tx = tid & 15, ty = tid >> 4;
    const long row0 = (long)blockIdx.x * 64;
    const int c0 = blockIdx.y * 64;
    const int lrow = tid >> 2;
    const int lk4 = (tid & 3) << 2;
    const float* wm[2] = {W, U};
    float acc[2][4][4] = {};

    for (int kk = 0; kk < DD; kk += 16) {
        float4 xv = *(const float4*)&x[(row0 + lrow) * DD + kk + lk4];
        xs[lk4+0][lrow] = xv.x; xs[lk4+1][lrow] = xv.y;
        xs[lk4+2][lrow] = xv.z; xs[lk4+3][lrow] = xv.w;
        #pragma unroll
        for (int j = 0; j < 2; ++j) {
            float4 wv4 = *(const float4*)&wm[j][(long)(c0 + lrow) * DD + kk + lk4];
            ws[j][lk4+0][lrow] = wv4.x; ws[j][lk4+1][lrow] = wv4.y;
            ws[j][lk4+2][lrow] = wv4.z; ws[j][lk4+3][lrow] = wv4.w;
        }
        __syncthreads();
        #pragma unroll
        for (int k = 0; k < 16; ++k) {
            float4 a4 = *(const float4*)&xs[k][ty << 2];
            float4 b0 = *(const float4*)&ws[0][k][tx << 2];
            float4 b1 = *(const float4*)&ws[1][k][tx << 2];
            float av[4] = {a4.x, a4.y, a4.z, a4.w};
            float bv0[4] = {b0.x, b0.y, b0.z, b0.w};
            float bv1[4] = {b1.x, b1.y, b1.z, b1.w};
            #pragma unroll
            for (int r = 0; r < 4; ++r)
                #pragma unroll
                for (int c = 0; c < 4; ++c) {
                    acc[0][r][c] += av[r] * bv0[c];
                    acc[1][r][c] += av[r] * bv1[c];
                }
        }
        __syncthreads();
    }
    float g0 = g[0];
    float4 bW4 = *(const float4*)&bW[c0 + (tx << 2)];
    float4 bU4 = *(const float4*)&bU[c0 + (tx << 2)];
    float bwa[4] = {bW4.x, bW4.y, bW4.z, bW4.w};
    float bua[4] = {bU4.x, bU4.y, bU4.z, bU4.w};
    #pragma unroll
    for (int r = 0; r < 4; ++r) {
        float pv[4];
        #pragma unroll
        for (int c = 0; c < 4; ++c) {
            float aw = acc[0][r][c] + bwa[c];
            float au = acc[1][r][c] + bua[c];
            pv[c] = g0 * tanhf(aw) * (1.f / (1.f + __expf(-au)));
        }
        long orow = (row0 + (ty << 2) + r) * DD + c0 + (tx << 2);
        *(float4*)&P[orow] = make_float4(pv[0], pv[1], pv[2], pv[3]);
    }
}

// ---------------- Banded decay attention (L=512, band=32) ----------------
// grid: (nseq, 8 row-tiles), block 256. 4 lanes/row, each owns 8 dims of head.
__global__ __launch_bounds__(256)
void attn(const float* __restrict__ Q, const float* __restrict__ K,
          const float* __restrict__ V, float* __restrict__ O)
{
    __shared__ __align__(16) float Kt[96][36];
    __shared__ __align__(16) float Vt[96][36];
    const int tid = threadIdx.x;
    const int rowIdx = tid >> 2;     // 0..63
    const int qq = tid & 3;          // dim quarter
    const int t0 = blockIdx.y * 64;
    const long sbase = (long)blockIdx.x * 512;
    const int lrem = 512 - t0;
    const int ktrows = lrem < 96 ? lrem : 96;

    for (int h = 0; h < 8; ++h) {
        #pragma unroll
        for (int it = 0; it < 3; ++it) {
            int idx = tid + it * 256;          // 0..767
            int kr = idx >> 3, d4 = (idx & 7) << 2;
            if (kr < ktrows) {
                long gr = (sbase + t0 + kr) * DD + h * 32 + d4;
                *(float4*)&Kt[kr][d4] = *(const float4*)&K[gr];
                *(float4*)&Vt[kr][d4] = *(const float4*)&V[gr];
            }
        }
        __syncthreads();

        float qr[8];
        {
            long gq_ = (sbase + t0 + rowIdx) * DD + h * 32 + (qq << 3);
            float4 a = *(const float4*)&Q[gq_];
            float4 b = *(const float4*)&Q[gq_ + 4];
            qr[0]=a.x; qr[1]=a.y; qr[2]=a.z; qr[3]=a.w;
            qr[4]=b.x; qr[5]=b.y; qr[6]=b.z; qr[7]=b.w;
        }
        float o[8] = {0.f,0.f,0.f,0.f,0.f,0.f,0.f,0.f};
        for (int dl = 0; dl < 32; ++dl) {
            int krow = rowIdx + dl;
            if (krow < ktrows) {
                const float* kp = &Kt[krow][qq << 3];
                float4 ka = *(const float4*)kp;
                float4 kb = *(const float4*)(kp + 4);
                float s = qr[0]*ka.x + qr[1]*ka.y + qr[2]*ka.z + qr[3]*ka.w
                        + qr[4]*kb.x + qr[5]*kb.y + qr[6]*kb.z + qr[7]*kb.w;
                s += __shfl_xor(s, 1, 64);
                s += __shfl_xor(s, 2, 64);
                s *= __expf(-(float)dl);
                const float* vp = &Vt[krow][qq << 3];
                float4 va = *(const float4*)vp;
                float4 vb = *(const float4*)(vp + 4);
                o[0] += s*va.x; o[1] += s*va.y; o[2] += s*va.z; o[3] += s*va.w;
                o[4] += s*vb.x; o[5] += s*vb.y; o[6] += s*vb.z; o[7] += s*vb.w;
            }
        }
        long go_ = (sbase + t0 + rowIdx) * DD + h * 32 + (qq << 3);
        *(float4*)&O[go_]     = make_float4(o[0], o[1], o[2], o[3]);
        *(float4*)&O[go_ + 4] = make_float4(o[4], o[5], o[6], o[7]);
        __syncthreads();
    }
}

// ---------------- Small dense attention for global retention (N=32) ----------------
__global__ __launch_bounds__(64)
void small_attn(const float* __restrict__ Q, const float* __restrict__ K,
                const float* __restrict__ V, float* __restrict__ O)
{
    int b = blockIdx.x >> 3, h = blockIdx.x & 7;
    int i = threadIdx.x;
    if (i >= 32) return;
    long base = (long)b * 32 * DD + h * 32;
    float qr[32], o[32];
    #pragma unroll
    for (int d4 = 0; d4 < 8; ++d4) {
        float4 t = *(const float4*)&Q[base + (long)i * DD + d4 * 4];
        qr[d4*4+0]=t.x; qr[d4*4+1]=t.y; qr[d4*4+2]=t.z; qr[d4*4+3]=t.w;
    }
    #pragma unroll
    for (int d = 0; d < 32; ++d) o[d] = 0.f;
    for (int j = i; j < 32; ++j) {
        float s = 0.f;
        #pragma unroll
        for (int d4 = 0; d4 < 8; ++d4) {
            float4 kv = *(const float4*)&K[base + (long)j * DD + d4 * 4];
            s += qr[d4*4+0]*kv.x + qr[d4*4+1]*kv.y + qr[d4*4+2]*kv.z + qr[d4*4+3]*kv.w;
        }
        s *= __expf(-(float)(j - i));
        #pragma unroll
        for (int d4 = 0; d4 < 8; ++d4) {
            float4 vv = *(const float4*)&V[base + (long)j * DD + d4 * 4];
            o[d4*4+0] += s*vv.x; o[d4*4+1] += s*vv.y; o[d4*4+2] += s*vv.z; o[d4*4+3] += s*vv.w;
        }
    }
    #pragma unroll
    for (int d4 = 0; d4 < 8; ++d4)
        *(float4*)&O[base + (long)i * DD + d4 * 4] = make_float4(o[d4*4+0], o[d4*4+1], o[d4*4+2], o[d4*4+3]);
}

// ---------------- GroupNorm(num_groups=1) over [n,256] per group, in-place ----------------
__global__ __launch_bounds__(256)
void groupnorm(float* __restrict__ buf, int n,
               const float* __restrict__ w, const float* __restrict__ b)
{
    const long ge = (long)n * DD;
    float* p = buf + (long)blockIdx.x * ge;
    float s = 0.f, ss = 0.f;
    for (long i = threadIdx.x; i < ge; i += 256) {
        float v = p[i];
        s += v; ss += v * v;
    }
    #pragma unroll
    for (int off = 32; off > 0; off >>= 1) {
        s  += __shfl_down(s, off, 64);
        ss += __shfl_down(ss, off, 64);
    }
    __shared__ float rs[4], rss[4];
    if ((threadIdx.x & 63) == 0) { rs[threadIdx.x >> 6] = s; rss[threadIdx.x >> 6] = ss; }
    __syncthreads();
    s = rs[0] + rs[1] + rs[2] + rs[3];
    ss = rss[0] + rss[1] + rss[2] + rss[3];
    float mean = s / (float)ge;
    float var = ss / (float)ge - mean * mean;
    float rsig = rsqrtf(var + 1e-5f);
    float wd = w[threadIdx.x], bd = b[threadIdx.x];
    for (long i = threadIdx.x; i < ge; i += 256)
        p[i] = (p[i] - mean) * rsig * wd + bd;
}

// ---------------- Softmax-pool: out[s,d] = sum_n softmax_n(P[s,n,d]) * X[s,n,d] ----------------
// |P| <= |g| ~ 0.2 so exp without max-subtraction is safe and matches softmax exactly.
__global__ __launch_bounds__(256)
void pool_reduce(const float* __restrict__ P, const float* __restrict__ X,
                 float* __restrict__ out, int n)
{
    int d = threadIdx.x;
    long base = (long)blockIdx.x * n * DD;
    float l = 0.f, acc = 0.f;
    for (int j = 0; j < n; ++j) {
        float pv = P[base + (long)j * DD + d];
        float xv = X[base + (long)j * DD + d];
        float e = __expf(pv);
        l += e; acc += e * xv;
    }
    out[(long)blockIdx.x * DD + d] = acc / l;
}

// ---------------- BatchNorm(batch=4, training stats) + classifier ----------------
__global__ __launch_bounds__(256)
void bn_cls(const float* __restrict__ emb, const float* __restrict__ bn_w,
            const float* __restrict__ bn_b, const float* __restrict__ cls_W,
            const float* __restrict__ cls_b, float* __restrict__ out)
{
    int d = threadIdx.x;
    float e0 = emb[d], e1 = emb[256 + d], e2 = emb[512 + d], e3 = emb[768 + d];
    float mu = 0.25f * (e0 + e1 + e2 + e3);
    float v0 = e0 - mu, v1 = e1 - mu, v2 = e2 - mu, v3 = e3 - mu;
    float var = 0.25f * (v0*v0 + v1*v1 + v2*v2 + v3*v3);
    float rs = rsqrtf(var + 1e-5f);
    float w = bn_w[d], bb = bn_b[d];
    float z0 = v0 * rs * w + bb, z1 = v1 * rs * w + bb;
    float z2 = v2 * rs * w + bb, z3 = v3 * rs * w + bb;
    float w0 = cls_W[d], w1 = cls_W[256 + d];
    __shared__ float red[8][256];
    red[0][d] = z0 * w0; red[1][d] = z0 * w1;
    red[2][d] = z1 * w0; red[3][d] = z1 * w1;
    red[4][d] = z2 * w0; red[5][d] = z2 * w1;
    red[6][d] = z3 * w0; red[7][d] = z3 * w1;
    __syncthreads();
    for (int off = 128; off > 0; off >>= 1) {
        if (d < off) {
            #pragma unroll
            for (int m = 0; m < 8; ++m) red[m][d] += red[m][d + off];
        }
        __syncthreads();
    }
    if (d < 8) out[d] = red[d][0] + cls_b[d & 1];
}

extern "C" void kernel_launch(void* const* d_in, const int* in_sizes, int n_in,
                              void* d_out, int out_size, void* d_ws, size_t ws_size,
                              hipStream_t stream)
{
    (void)in_sizes; (void)n_in; (void)out_size;
#define F(i) ((const float*)d_in[i])
    const float* bags = F(0);

    // Choose sequence-chunking so 4 big buffers + ~1MB small fit in ws.
    int nch = 1;
    while (nch < 128) {
        size_t cb = ((size_t)(128 / nch)) * 512 * 256 * 4ull;
        if (4 * cb + (1u << 20) <= ws_size) break;
        nch <<= 1;
    }
    const int cseq = 128 / nch;
    const int crows = cseq * 512;
    const size_t cbf = (size_t)crows * 256;     // floats per big buffer

    float* Xc = (float*)d_ws;
    float* Qc = Xc + cbf;
    float* Kc = Xc + 2 * cbf;
    float* Vc = Xc + 3 * cbf;
    float* Pc = Qc;                             // pool gate reuses Q (QKV dead by then)
    float* smallb = Xc + 4 * cbf;
    float* local = smallb;                      // 128*256
    float* gq = smallb + 1 * 32768;
    float* gk = smallb + 2 * 32768;
    float* gv = smallb + 3 * 32768;
    float* go = smallb + 4 * 32768;
    float* gp = smallb + 5 * 32768;
    float* embb = smallb + 6 * 32768;           // 4*256

    dim3 blk(256), ggemm(crows / 64, 4);
    for (int c = 0; c < nch; ++c) {
        const float* xin = bags + (size_t)c * cbf;
        // retention 1 (input from bags, output into Xc)
        qkv_gemm<<<ggemm, blk, 0, stream>>>(xin, F(1), F(2), F(3), F(4), F(5), F(6), Qc, Kc, Vc);
        attn<<<dim3(cseq, 8), blk, 0, stream>>>(Qc, Kc, Vc, Xc);
        groupnorm<<<cseq, blk, 0, stream>>>(Xc, 512, F(7), F(8));
        // retention 2 (in-place on Xc)
        qkv_gemm<<<ggemm, blk, 0, stream>>>(Xc, F(9), F(10), F(11), F(12), F(13), F(14), Qc, Kc, Vc);
        attn<<<dim3(cseq, 8), blk, 0, stream>>>(Qc, Kc, Vc, Xc);
        groupnorm<<<cseq, blk, 0, stream>>>(Xc, 512, F(15), F(16));
        // local pool
        pool_gemm<<<ggemm, blk, 0, stream>>>(Xc, F(25), F(26), F(27), F(28), F(29), Pc);
        pool_reduce<<<cseq, blk, 0, stream>>>(Pc, Xc, local + (size_t)c * cseq * 256, 512);
    }
    // global retention on local [4 x 32 x 256]
    qkv_gemm<<<dim3(2, 4), blk, 0, stream>>>(local, F(17), F(18), F(19), F(20), F(21), F(22), gq, gk, gv);
    small_attn<<<32, 64, 0, stream>>>(gq, gk, gv, go);
    groupnorm<<<4, blk, 0, stream>>>(go, 32, F(23), F(24));
    // global pool
    pool_gemm<<<dim3(2, 4), blk, 0, stream>>>(go, F(30), F(31), F(32), F(33), F(34), gp);
    pool_reduce<<<4, blk, 0, stream>>>(gp, go, embb, 32);
    // batchnorm + classifier
    bn_cls<<<1, blk, 0, stream>>>(embb, F(35), F(36), F(37), F(38), (float*)d_out);
#undef F
}

// Round 2
// 842.797 us; speedup vs baseline: 2.7313x; 2.7313x over previous
//
#include <hip/hip_runtime.h>

typedef unsigned int uint;
typedef unsigned short ushort;
typedef __attribute__((ext_vector_type(8))) short short8;
typedef __attribute__((ext_vector_type(8))) ushort ushort8;
typedef __attribute__((ext_vector_type(4))) float f32x4;

#define DD 256

__device__ __forceinline__ float b2f(ushort u) {
    return __uint_as_float(((uint)u) << 16);
}
__device__ __forceinline__ ushort f2b(float f) {
    uint u = __float_as_uint(f);
    u += 0x7FFFu + ((u >> 16) & 1u);
    return (ushort)(u >> 16);
}

// ======================= weight hi/lo pre-split =======================
struct WPtrs { const float* w[13]; };

__global__ __launch_bounds__(256) void wcvt(WPtrs p, ushort* __restrict__ out)
{
    int idx = blockIdx.x * 256 + threadIdx.x;    // float4 index; 13*16384 total
    int mat = idx >> 14;
    int off = idx & 16383;
    float4 v = *((const float4*)p.w[mat] + off);
    float xs[4] = {v.x, v.y, v.z, v.w};
    ushort h[4], l[4];
    #pragma unroll
    for (int i = 0; i < 4; ++i) {
        uint u = __float_as_uint(xs[i]);
        uint hr = (u + 0x7FFFu + ((u >> 16) & 1u)) & 0xFFFF0000u;
        h[i] = (ushort)(hr >> 16);
        float rem = xs[i] - __uint_as_float(hr);
        l[i] = (ushort)(__float_as_uint(rem) >> 16);
    }
    ushort4 hv = make_ushort4(h[0], h[1], h[2], h[3]);
    ushort4 lv = make_ushort4(l[0], l[1], l[2], l[3]);
    *((ushort4*)(out + (size_t)mat * 131072) + off) = hv;
    *((ushort4*)(out + (size_t)mat * 131072 + 65536) + off) = lv;
}

// ======================= MFMA split-bf16 GEMM =======================
// C[r][c] = sum_k X[r][k] * W[c][k] + bias[c]   (X: [R][256] fp32, W pre-split hi/lo bf16)
// block tile 128x256 (full N), wave tile 64x128, k-chunk 32. grid (R/128, nmat).
struct GemmPtrs {
    const float* X;
    const ushort* W0; const ushort* W1; const ushort* W2;   // each [2][256][256]
    const float* b0; const float* b1; const float* b2;
    void* o0; void* o1; void* o2;
    int bf16mask;
};

__global__ __launch_bounds__(256, 2) void gemm_mfma(GemmPtrs p)
{
    __shared__ __align__(16) short As[2][128][40];
    __shared__ __align__(16) short Bs[2][256][40];
    const int tid = threadIdx.x;
    const int w = tid >> 6, lane = tid & 63;
    const int quad = lane >> 4, r16 = lane & 15;
    const long row0 = (long)blockIdx.x * 128;
    const int mat = blockIdx.y;
    const ushort* W = (mat == 0) ? p.W0 : (mat == 1 ? p.W1 : p.W2);
    const float* bias = (mat == 0) ? p.b0 : (mat == 1 ? p.b1 : p.b2);
    void* out = (mat == 0) ? p.o0 : (mat == 1 ? p.o1 : p.o2);
    const int isbf = (p.bf16mask >> mat) & 1;
    const int wrow = (w & 1) * 64;
    const int wcol = (w >> 1) * 128;

    f32x4 acc[4][8];
    #pragma unroll
    for (int rt = 0; rt < 4; ++rt)
        #pragma unroll
        for (int ct = 0; ct < 8; ++ct)
            acc[rt][ct] = (f32x4){0.f, 0.f, 0.f, 0.f};

    const int arow = tid >> 1;
    const int kb = (tid & 1) << 4;
    const float* abase = p.X + (row0 + arow) * DD + kb;
    const short* wb = (const short*)W + tid * DD;

    for (int kc = 0; kc < 8; ++kc) {
        __syncthreads();
        // ---- stage A with hi/lo split (16 floats/thread) ----
        {
            const float* src = abase + kc * 32;
            #pragma unroll
            for (int gx = 0; gx < 2; ++gx) {
                float4 x0 = *(const float4*)(src + gx * 8);
                float4 x1 = *(const float4*)(src + gx * 8 + 4);
                float xs[8] = {x0.x, x0.y, x0.z, x0.w, x1.x, x1.y, x1.z, x1.w};
                short h[8], l[8];
                #pragma unroll
                for (int i = 0; i < 8; ++i) {
                    uint u = __float_as_uint(xs[i]);
                    uint hr = (u + 0x7FFFu + ((u >> 16) & 1u)) & 0xFFFF0000u;
                    h[i] = (short)(hr >> 16);
                    float rem = xs[i] - __uint_as_float(hr);
                    l[i] = (short)(__float_as_uint(rem) >> 16);
                }
                short8 hv = {h[0], h[1], h[2], h[3], h[4], h[5], h[6], h[7]};
                short8 lv = {l[0], l[1], l[2], l[3], l[4], l[5], l[6], l[7]};
                *(short8*)&As[0][arow][kb + gx * 8] = hv;
                *(short8*)&As[1][arow][kb + gx * 8] = lv;
            }
        }
        // ---- stage B (pre-split bf16, pure copy) ----
        {
            const short* srcH = wb + kc * 32;
            const short* srcL = srcH + 65536;
            #pragma unroll
            for (int gx = 0; gx < 4; ++gx) {
                *(short8*)&Bs[0][tid][gx * 8] = *(const short8*)(srcH + gx * 8);
                *(short8*)&Bs[1][tid][gx * 8] = *(const short8*)(srcL + gx * 8);
            }
        }
        __syncthreads();
        // ---- MFMA ----
        short8 af[4][2];
        #pragma unroll
        for (int rt = 0; rt < 4; ++rt) {
            const int rr = wrow + rt * 16 + r16;
            af[rt][0] = *(const short8*)&As[0][rr][quad * 8];
            af[rt][1] = *(const short8*)&As[1][rr][quad * 8];
        }
        #pragma unroll
        for (int ct = 0; ct < 8; ++ct) {
            const int cc = wcol + ct * 16 + r16;
            short8 bh = *(const short8*)&Bs[0][cc][quad * 8];
            short8 bl = *(const short8*)&Bs[1][cc][quad * 8];
            #pragma unroll
            for (int rt = 0; rt < 4; ++rt) {
                acc[rt][ct] = __builtin_amdgcn_mfma_f32_16x16x32_bf16(af[rt][0], bh, acc[rt][ct], 0, 0, 0);
                acc[rt][ct] = __builtin_amdgcn_mfma_f32_16x16x32_bf16(af[rt][0], bl, acc[rt][ct], 0, 0, 0);
                acc[rt][ct] = __builtin_amdgcn_mfma_f32_16x16x32_bf16(af[rt][1], bh, acc[rt][ct], 0, 0, 0);
            }
        }
    }
    // ---- epilogue: C layout col=lane&15, row=quad*4+reg ----
    #pragma unroll
    for (int ct = 0; ct < 8; ++ct) {
        const int col = wcol + ct * 16 + r16;
        const float bv = bias[col];
        #pragma unroll
        for (int rt = 0; rt < 4; ++rt) {
            const long rb = row0 + wrow + rt * 16 + quad * 4;
            f32x4 a = acc[rt][ct];
            if (isbf) {
                ushort* o = (ushort*)out;
                #pragma unroll
                for (int i = 0; i < 4; ++i) o[(rb + i) * DD + col] = f2b(a[i] + bv);
            } else {
                float* o = (float*)out;
                #pragma unroll
                for (int i = 0; i < 4; ++i) o[(rb + i) * DD + col] = a[i] + bv;
            }
        }
    }
}

// ======================= banded decay attention (band=32), K/V bf16 =======================
__global__ __launch_bounds__(256) void attn(const float* __restrict__ Q, const ushort* __restrict__ K,
                                            const ushort* __restrict__ V, float* __restrict__ O)
{
    __shared__ __align__(16) float Kt[96][36];
    __shared__ __align__(16) float Vt[96][36];
    const int tid = threadIdx.x;
    const int rowIdx = tid >> 2;
    const int qq = tid & 3;
    const int t0 = blockIdx.y * 64;
    const long sbase = (long)blockIdx.x * 512;
    const int lrem = 512 - t0;
    const int ktrows = lrem < 96 ? lrem : 96;

    for (int h = 0; h < 8; ++h) {
        #pragma unroll
        for (int it = 0; it < 3; ++it) {
            int idx = tid + it * 256;          // 0..767 = 96 rows x 8 dim-groups
            int kr = idx >> 3, d4 = (idx & 7) << 2;
            if (kr < ktrows) {
                long gr = (sbase + t0 + kr) * DD + h * 32 + d4;
                ushort4 kv = *(const ushort4*)&K[gr];
                ushort4 vv = *(const ushort4*)&V[gr];
                *(float4*)&Kt[kr][d4] = make_float4(b2f(kv.x), b2f(kv.y), b2f(kv.z), b2f(kv.w));
                *(float4*)&Vt[kr][d4] = make_float4(b2f(vv.x), b2f(vv.y), b2f(vv.z), b2f(vv.w));
            }
        }
        __syncthreads();

        float qr[8];
        {
            long gq_ = (sbase + t0 + rowIdx) * DD + h * 32 + (qq << 3);
            float4 a = *(const float4*)&Q[gq_];
            float4 b = *(const float4*)&Q[gq_ + 4];
            qr[0] = a.x; qr[1] = a.y; qr[2] = a.z; qr[3] = a.w;
            qr[4] = b.x; qr[5] = b.y; qr[6] = b.z; qr[7] = b.w;
        }
        float o[8] = {0.f, 0.f, 0.f, 0.f, 0.f, 0.f, 0.f, 0.f};
        for (int dl = 0; dl < 32; ++dl) {
            int krow = rowIdx + dl;
            if (krow < ktrows) {
                const float* kp = &Kt[krow][qq << 3];
                float4 ka = *(const float4*)kp;
                float4 kb2 = *(const float4*)(kp + 4);
                float s = qr[0]*ka.x + qr[1]*ka.y + qr[2]*ka.z + qr[3]*ka.w
                        + qr[4]*kb2.x + qr[5]*kb2.y + qr[6]*kb2.z + qr[7]*kb2.w;
                s += __shfl_xor(s, 1, 64);
                s += __shfl_xor(s, 2, 64);
                s *= __expf(-(float)dl);
                const float* vp = &Vt[krow][qq << 3];
                float4 va = *(const float4*)vp;
                float4 vb = *(const float4*)(vp + 4);
                o[0] += s*va.x; o[1] += s*va.y; o[2] += s*va.z; o[3] += s*va.w;
                o[4] += s*vb.x; o[5] += s*vb.y; o[6] += s*vb.z; o[7] += s*vb.w;
            }
        }
        long go_ = (sbase + t0 + rowIdx) * DD + h * 32 + (qq << 3);
        *(float4*)&O[go_]     = make_float4(o[0], o[1], o[2], o[3]);
        *(float4*)&O[go_ + 4] = make_float4(o[4], o[5], o[6], o[7]);
        __syncthreads();
    }
}

// ======================= small dense attention (N=32), K/V bf16 =======================
__global__ __launch_bounds__(64) void small_attn(const float* __restrict__ Q, const ushort* __restrict__ K,
                                                 const ushort* __restrict__ V, float* __restrict__ O)
{
    int b = blockIdx.x >> 3, h = blockIdx.x & 7;
    int i = threadIdx.x;
    if (i >= 32) return;
    long base = (long)b * 32 * DD + h * 32;
    float qr[32], o[32];
    #pragma unroll
    for (int d4 = 0; d4 < 8; ++d4) {
        float4 t = *(const float4*)&Q[base + (long)i * DD + d4 * 4];
        qr[d4*4+0] = t.x; qr[d4*4+1] = t.y; qr[d4*4+2] = t.z; qr[d4*4+3] = t.w;
    }
    #pragma unroll
    for (int d = 0; d < 32; ++d) o[d] = 0.f;
    for (int j = i; j < 32; ++j) {
        float s = 0.f;
        #pragma unroll
        for (int d4 = 0; d4 < 8; ++d4) {
            ushort4 kv = *(const ushort4*)&K[base + (long)j * DD + d4 * 4];
            s += qr[d4*4+0]*b2f(kv.x) + qr[d4*4+1]*b2f(kv.y) + qr[d4*4+2]*b2f(kv.z) + qr[d4*4+3]*b2f(kv.w);
        }
        s *= __expf(-(float)(j - i));
        #pragma unroll
        for (int d4 = 0; d4 < 8; ++d4) {
            ushort4 vv = *(const ushort4*)&V[base + (long)j * DD + d4 * 4];
            o[d4*4+0] += s*b2f(vv.x); o[d4*4+1] += s*b2f(vv.y); o[d4*4+2] += s*b2f(vv.z); o[d4*4+3] += s*b2f(vv.w);
        }
    }
    #pragma unroll
    for (int d4 = 0; d4 < 8; ++d4)
        *(float4*)&O[base + (long)i * DD + d4 * 4] = make_float4(o[d4*4+0], o[d4*4+1], o[d4*4+2], o[d4*4+3]);
}

// ======================= GroupNorm, 3-phase =======================
__global__ __launch_bounds__(256) void gn_stats(const float* __restrict__ buf, float2* __restrict__ part, int rpb)
{
    const int s = blockIdx.x, ch = blockIdx.y, NC = gridDim.y;
    const long base = ((long)s * NC + ch) * rpb * DD;
    const float4* p = (const float4*)(buf + base);
    const int nf4 = rpb * 64;
    float sm = 0.f, ss = 0.f;
    for (int i = threadIdx.x; i < nf4; i += 256) {
        float4 v = p[i];
        sm += v.x + v.y + v.z + v.w;
        ss += v.x*v.x + v.y*v.y + v.z*v.z + v.w*v.w;
    }
    #pragma unroll
    for (int off = 32; off > 0; off >>= 1) {
        sm += __shfl_down(sm, off, 64);
        ss += __shfl_down(ss, off, 64);
    }
    __shared__ float rs[4], rss[4];
    if ((threadIdx.x & 63) == 0) { rs[threadIdx.x >> 6] = sm; rss[threadIdx.x >> 6] = ss; }
    __syncthreads();
    if (threadIdx.x == 0) {
        part[s * NC + ch] = make_float2(rs[0]+rs[1]+rs[2]+rs[3], rss[0]+rss[1]+rss[2]+rss[3]);
    }
}

__global__ __launch_bounds__(256) void gn_final(const float2* __restrict__ part, float2* __restrict__ stats,
                                                int ng, int NC, float invN)
{
    int t = threadIdx.x;
    if (t < ng) {
        float sm = 0.f, ss = 0.f;
        for (int c = 0; c < NC; ++c) {
            float2 p = part[t * NC + c];
            sm += p.x; ss += p.y;
        }
        float mean = sm * invN;
        float var = ss * invN - mean * mean;
        stats[t] = make_float2(mean, rsqrtf(var + 1e-5f));
    }
}

__global__ __launch_bounds__(256) void gn_apply(float* __restrict__ buf, const float2* __restrict__ stats,
                                                const float* __restrict__ w, const float* __restrict__ b, int shift)
{
    long i = (long)blockIdx.x * 256 + threadIdx.x;     // float4 index
    long e = i * 4;
    int seq = (int)(e >> shift);
    int d0 = (int)(e & 255);
    float2 st = stats[seq];
    float4 v = ((const float4*)buf)[i];
    float4 wv = *(const float4*)&w[d0];
    float4 bv = *(const float4*)&b[d0];
    v.x = (v.x - st.x) * st.y * wv.x + bv.x;
    v.y = (v.y - st.x) * st.y * wv.y + bv.y;
    v.z = (v.z - st.x) * st.y * wv.z + bv.z;
    v.w = (v.w - st.x) * st.y * wv.w + bv.w;
    ((float4*)buf)[i] = v;
}

// ======================= softmax-pool, 2-phase =======================
__global__ __launch_bounds__(256) void pool_partial(const float* __restrict__ AW, const float* __restrict__ AU,
                                                    const float* __restrict__ X, const float* __restrict__ g,
                                                    float* __restrict__ part, int rpb)
{
    const int s = blockIdx.x, ch = blockIdx.y, NC = gridDim.y, d = threadIdx.x;
    const long rowbase = ((long)s * NC + ch) * rpb;
    const float g0 = g[0];
    float l = 0.f, acc = 0.f;
    for (int j = 0; j < rpb; ++j) {
        long idx = (rowbase + j) * DD + d;
        float aw = AW[idx], au = AU[idx], x = X[idx];
        float a = g0 * tanhf(aw) * (1.f / (1.f + __expf(-au)));
        float e = __expf(a);
        l += e; acc += e * x;
    }
    long pbase = (long)(s * NC + ch) * 512;
    part[pbase + d] = l;
    part[pbase + 256 + d] = acc;
}

__global__ __launch_bounds__(256) void pool_final(const float* __restrict__ part, float* __restrict__ out, int NC)
{
    const int s = blockIdx.x, d = threadIdx.x;
    float l = 0.f, acc = 0.f;
    for (int c = 0; c < NC; ++c) {
        long pbase = (long)(s * NC + c) * 512;
        l += part[pbase + d];
        acc += part[pbase + 256 + d];
    }
    out[(long)s * DD + d] = acc / l;
}

// ======================= BatchNorm + classifier =======================
__global__ __launch_bounds__(256) void bn_cls(const float* __restrict__ emb, const float* __restrict__ bn_w,
                                              const float* __restrict__ bn_b, const float* __restrict__ cls_W,
                                              const float* __restrict__ cls_b, float* __restrict__ out)
{
    int d = threadIdx.x;
    float e0 = emb[d], e1 = emb[256 + d], e2 = emb[512 + d], e3 = emb[768 + d];
    float mu = 0.25f * (e0 + e1 + e2 + e3);
    float v0 = e0 - mu, v1 = e1 - mu, v2 = e2 - mu, v3 = e3 - mu;
    float var = 0.25f * (v0*v0 + v1*v1 + v2*v2 + v3*v3);
    float rs = rsqrtf(var + 1e-5f);
    float w = bn_w[d], bb = bn_b[d];
    float z0 = v0*rs*w + bb, z1 = v1*rs*w + bb, z2 = v2*rs*w + bb, z3 = v3*rs*w + bb;
    float w0 = cls_W[d], w1 = cls_W[256 + d];
    __shared__ float red[8][256];
    red[0][d] = z0*w0; red[1][d] = z0*w1;
    red[2][d] = z1*w0; red[3][d] = z1*w1;
    red[4][d] = z2*w0; red[5][d] = z2*w1;
    red[6][d] = z3*w0; red[7][d] = z3*w1;
    __syncthreads();
    for (int off = 128; off > 0; off >>= 1) {
        if (d < off) {
            #pragma unroll
            for (int m = 0; m < 8; ++m) red[m][d] += red[m][d + off];
        }
        __syncthreads();
    }
    if (d < 8) out[d] = red[d][0] + cls_b[d & 1];
}

// ======================= host =======================
extern "C" void kernel_launch(void* const* d_in, const int* in_sizes, int n_in,
                              void* d_out, int out_size, void* d_ws, size_t ws_size,
                              hipStream_t stream)
{
    (void)in_sizes; (void)n_in; (void)out_size;
#define F(i) ((const float*)d_in[i])
    const float* bags = F(0);

    const size_t smallF = 1576192;   // floats reserved for small buffers
    int nch = 1;
    while (nch < 128) {
        size_t bigF = ((size_t)(128 / nch)) * 512 * 256;
        if ((3 * bigF + smallF) * 4 <= ws_size) break;
        nch <<= 1;
    }
    const int cseq = 128 / nch;
    const size_t crows = (size_t)cseq * 512;
    const size_t bigF = crows * 256;

    float* Xb = (float*)d_ws;
    float* Qb = Xb + bigF;
    float* KVb = Xb + 2 * bigF;               // K bf16 then V bf16; also AU (fp32 view)
    ushort* Kb = (ushort*)KVb;
    ushort* Vb = Kb + crows * 256;
    float* sm = Xb + 3 * bigF;
    ushort* wsW = (ushort*)sm;                // 13 * 131072 ushorts = 851968 floats
    float* local_ = sm + 851968;
    float* gq   = local_ + 32768;
    float* gkv  = gq + 32768;
    ushort* gkb = (ushort*)gkv;
    ushort* gvb = gkb + 32768;
    float* go   = gkv + 32768;
    float* AWg  = go + 32768;
    float* AUg  = AWg + 32768;
    float* embb = AUg + 32768;
    float2* gnpart  = (float2*)(embb + 1024);  // up to 1024 groups
    float2* gnstats = gnpart + 1024;
    float* ppart = (float*)(gnstats + 128);    // [1024][512]

    // weight pre-split: mats {r1 QKV, r2 QKV, rg QKV, pl WU, pg WU}
    WPtrs wp;
    const int widx[13] = {1, 3, 5, 9, 11, 13, 17, 19, 21, 25, 27, 30, 32};
    for (int i = 0; i < 13; ++i) wp.w[i] = F(widx[i]);
    wcvt<<<832, 256, 0, stream>>>(wp, wsW);

    dim3 blk(256);
    const int gx = (int)(crows / 128);

    for (int c = 0; c < nch; ++c) {
        const float* xin = bags + (size_t)c * bigF;
        GemmPtrs g1 = {xin, wsW + 0*131072, wsW + 1*131072, wsW + 2*131072,
                       F(2), F(4), F(6), Qb, Kb, Vb, 0b110};
        gemm_mfma<<<dim3(gx, 3), blk, 0, stream>>>(g1);
        attn<<<dim3(cseq, 8), blk, 0, stream>>>(Qb, Kb, Vb, Xb);
        gn_stats<<<dim3(cseq, 8), blk, 0, stream>>>(Xb, gnpart, 64);
        gn_final<<<1, blk, 0, stream>>>(gnpart, gnstats, cseq, 8, 1.f / 131072.f);
        gn_apply<<<cseq * 128, blk, 0, stream>>>(Xb, gnstats, F(7), F(8), 17);

        GemmPtrs g2 = {Xb, wsW + 3*131072, wsW + 4*131072, wsW + 5*131072,
                       F(10), F(12), F(14), Qb, Kb, Vb, 0b110};
        gemm_mfma<<<dim3(gx, 3), blk, 0, stream>>>(g2);
        attn<<<dim3(cseq, 8), blk, 0, stream>>>(Qb, Kb, Vb, Xb);
        gn_stats<<<dim3(cseq, 8), blk, 0, stream>>>(Xb, gnpart, 64);
        gn_final<<<1, blk, 0, stream>>>(gnpart, gnstats, cseq, 8, 1.f / 131072.f);
        gn_apply<<<cseq * 128, blk, 0, stream>>>(Xb, gnstats, F(15), F(16), 17);

        GemmPtrs gp = {Xb, wsW + 9*131072, wsW + 10*131072, nullptr,
                       F(26), F(28), nullptr, Qb, KVb, nullptr, 0};
        gemm_mfma<<<dim3(gx, 2), blk, 0, stream>>>(gp);
        pool_partial<<<dim3(cseq, 8), blk, 0, stream>>>(Qb, KVb, Xb, F(29), ppart, 64);
        pool_final<<<cseq, blk, 0, stream>>>(ppart, local_ + (size_t)c * cseq * 256, 8);
    }

    // global retention on local [4 x 32 x 256] = 128 rows
    GemmPtrs gg = {local_, wsW + 6*131072, wsW + 7*131072, wsW + 8*131072,
                   F(18), F(20), F(22), gq, gkb, gvb, 0b110};
    gemm_mfma<<<dim3(1, 3), blk, 0, stream>>>(gg);
    small_attn<<<32, 64, 0, stream>>>(gq, gkb, gvb, go);
    gn_stats<<<dim3(4, 1), blk, 0, stream>>>(go, gnpart, 32);
    gn_final<<<1, blk, 0, stream>>>(gnpart, gnstats, 4, 1, 1.f / 8192.f);
    gn_apply<<<32, blk, 0, stream>>>(go, gnstats, F(23), F(24), 13);

    GemmPtrs gpg = {go, wsW + 11*131072, wsW + 12*131072, nullptr,
                    F(31), F(33), nullptr, AWg, AUg, nullptr, 0};
    gemm_mfma<<<dim3(1, 2), blk, 0, stream>>>(gpg);
    pool_partial<<<dim3(4, 1), blk, 0, stream>>>(AWg, AUg, go, F(34), ppart, 32);
    pool_final<<<4, blk, 0, stream>>>(ppart, embb, 1);

    bn_cls<<<1, blk, 0, stream>>>(embb, F(35), F(36), F(37), F(38), (float*)d_out);
#undef F
}

// Round 3
// 823.551 us; speedup vs baseline: 2.7951x; 1.0234x over previous
//
#include <hip/hip_runtime.h>

typedef unsigned int uint;
typedef unsigned short ushort;
typedef __attribute__((ext_vector_type(8))) short short8;
typedef __attribute__((ext_vector_type(4))) float f32x4;

#define DD 256
#define GAS __attribute__((address_space(1)))
#define LAS __attribute__((address_space(3)))

__device__ __forceinline__ float b2f(ushort u) {
    return __uint_as_float(((uint)u) << 16);
}
__device__ __forceinline__ ushort f2b(float f) {
    uint u = __float_as_uint(f);
    u += 0x7FFFu + ((u >> 16) & 1u);
    return (ushort)(u >> 16);
}
__device__ __forceinline__ void split2(float x, short& h, short& l) {
    uint u = __float_as_uint(x);
    uint hr = (u + 0x7FFFu + ((u >> 16) & 1u)) & 0xFFFF0000u;
    h = (short)(hr >> 16);
    l = (short)(__float_as_uint(x - __uint_as_float(hr)) >> 16);
}

// ======================= weight pre-split, old row-major layout (small path) =======================
struct WPtrs5 { const float* w[5]; };

__global__ __launch_bounds__(256) void wcvt_old(WPtrs5 p, ushort* __restrict__ out)
{
    int idx = blockIdx.x * 256 + threadIdx.x;    // float4 index; 5*16384 total
    int mat = idx >> 14;
    int off = idx & 16383;
    float4 v = *((const float4*)p.w[mat] + off);
    float xs[4] = {v.x, v.y, v.z, v.w};
    ushort h[4], l[4];
    #pragma unroll
    for (int i = 0; i < 4; ++i) {
        short hh, ll;
        split2(xs[i], hh, ll);
        h[i] = (ushort)hh; l[i] = (ushort)ll;
    }
    *((ushort4*)(out + (size_t)mat * 131072) + off) = make_ushort4(h[0], h[1], h[2], h[3]);
    *((ushort4*)(out + (size_t)mat * 131072 + 65536) + off) = make_ushort4(l[0], l[1], l[2], l[3]);
}

// ======================= weight pre-split, MFMA-fragment order (big path) =======================
// Wfrag[mat][hilo][kc8][nt16][lane64][8]: lane holds W[n=nt*16+(l&15)][k=kc*32+(l>>4)*8 + j]
struct WPtrs8 { const float* w[8]; };

__global__ __launch_bounds__(256) void wcvt_frag(WPtrs8 p, ushort* __restrict__ out)
{
    int idx = blockIdx.x * 256 + threadIdx.x;    // 8*2*8*16*64 = 131072 total
    int lane = idx & 63;
    int rest = idx >> 6;
    int nt = rest & 15;
    int kc = (rest >> 4) & 7;
    int hilo = (rest >> 7) & 1;
    int mat = rest >> 8;
    int n = nt * 16 + (lane & 15);
    int k = kc * 32 + (lane >> 4) * 8;
    const float* src = p.w[mat] + n * DD + k;
    float4 x0 = *(const float4*)src;
    float4 x1 = *(const float4*)(src + 4);
    float xs[8] = {x0.x, x0.y, x0.z, x0.w, x1.x, x1.y, x1.z, x1.w};
    short o8[8];
    #pragma unroll
    for (int i = 0; i < 8; ++i) {
        short h, l;
        split2(xs[i], h, l);
        o8[i] = hilo ? l : h;
    }
    short8 v = {o8[0], o8[1], o8[2], o8[3], o8[4], o8[5], o8[6], o8[7]};
    *(short8*)(out + (size_t)mat * 131072 + ((((hilo * 8 + kc) * 16 + nt) << 9) + lane * 8)) = v;
}

// ======================= big MFMA GEMM: async-B, reg-A, fused GN on input =======================
struct GemmBig {
    const float* X;            // raw rows [R][256] fp32
    const float2* stats;       // per-seq (mean, rsig) or nullptr
    const float* gnw; const float* gnb;
    const ushort* W;           // fragment-ordered, mats consecutive (131072 shorts each)
    const float* b0; const float* b1; const float* b2;
    void* o0; void* o1; void* o2;
    int bf16mask;
};

__global__ __launch_bounds__(256, 2) void gemm_big(GemmBig p)
{
    __shared__ __align__(16) ushort Bs[16384];   // [hilo2][nt16][lane64][8] = 32 KB
    const int tid = threadIdx.x, w = tid >> 6, lane = tid & 63;
    const int quad = lane >> 4, r16 = lane & 15;
    const long row0 = (long)blockIdx.x * 128;
    const int mat = blockIdx.y;
    const ushort* Wm = p.W + (size_t)mat * 131072;
    const float* bias = (mat == 0) ? p.b0 : (mat == 1 ? p.b1 : p.b2);
    void* out = (mat == 0) ? p.o0 : (mat == 1 ? p.o1 : p.o2);
    const int isbf = (p.bf16mask >> mat) & 1;
    const int wrow = (w & 1) * 64, wcol = (w >> 1) * 128;
    const bool gn = (p.stats != nullptr);

    float mu[4], rsg[4];
    #pragma unroll
    for (int mt = 0; mt < 4; ++mt) {
        long r = row0 + wrow + mt * 16 + r16;
        if (gn) { float2 st = p.stats[r >> 9]; mu[mt] = st.x; rsg[mt] = st.y; }
        else    { mu[mt] = 0.f; rsg[mt] = 1.f; }
    }

    f32x4 acc[4][8];
    #pragma unroll
    for (int mt = 0; mt < 4; ++mt)
        #pragma unroll
        for (int ct = 0; ct < 8; ++ct)
            acc[mt][ct] = (f32x4){0.f, 0.f, 0.f, 0.f};

    for (int kc = 0; kc < 8; ++kc) {
        // ---- async-stage B fragments (8 x 1KB per wave) ----
        #pragma unroll
        for (int i = 0; i < 8; ++i) {
            int c = i * 4 + w;
            int hilo = c >> 4, nt = c & 15;
            const ushort* g = Wm + ((((hilo * 8 + kc) * 16 + nt) << 9) + lane * 8);
            const ushort* l = &Bs[(hilo * 16 + nt) << 9];
            __builtin_amdgcn_global_load_lds((const GAS uint*)g, (LAS uint*)l, 16, 0, 0);
        }
        // ---- A fragments direct from global + fused GN + hi/lo split ----
        float gw[8], gb[8];
        if (gn) {
            int k = kc * 32 + quad * 8;
            float4 a0 = *(const float4*)&p.gnw[k], a1 = *(const float4*)&p.gnw[k + 4];
            float4 b0 = *(const float4*)&p.gnb[k], b1 = *(const float4*)&p.gnb[k + 4];
            gw[0]=a0.x; gw[1]=a0.y; gw[2]=a0.z; gw[3]=a0.w; gw[4]=a1.x; gw[5]=a1.y; gw[6]=a1.z; gw[7]=a1.w;
            gb[0]=b0.x; gb[1]=b0.y; gb[2]=b0.z; gb[3]=b0.w; gb[4]=b1.x; gb[5]=b1.y; gb[6]=b1.z; gb[7]=b1.w;
        }
        short8 ah[4], al[4];
        #pragma unroll
        for (int mt = 0; mt < 4; ++mt) {
            const float* ap = p.X + (row0 + wrow + mt * 16 + r16) * DD + kc * 32 + quad * 8;
            float4 x0 = *(const float4*)ap;
            float4 x1 = *(const float4*)(ap + 4);
            float xs[8] = {x0.x, x0.y, x0.z, x0.w, x1.x, x1.y, x1.z, x1.w};
            if (gn) {
                #pragma unroll
                for (int j = 0; j < 8; ++j) xs[j] = (xs[j] - mu[mt]) * rsg[mt] * gw[j] + gb[j];
            }
            short h[8], l8[8];
            #pragma unroll
            for (int j = 0; j < 8; ++j) split2(xs[j], h[j], l8[j]);
            ah[mt] = (short8){h[0], h[1], h[2], h[3], h[4], h[5], h[6], h[7]};
            al[mt] = (short8){l8[0], l8[1], l8[2], l8[3], l8[4], l8[5], l8[6], l8[7]};
        }
        __syncthreads();
        // ---- MFMA ----
        #pragma unroll
        for (int ct = 0; ct < 8; ++ct) {
            int nt = (wcol >> 4) + ct;
            short8 bh = *(const short8*)&Bs[(nt << 9) + lane * 8];
            short8 bl = *(const short8*)&Bs[((16 + nt) << 9) + lane * 8];
            #pragma unroll
            for (int mt = 0; mt < 4; ++mt) {
                acc[mt][ct] = __builtin_amdgcn_mfma_f32_16x16x32_bf16(ah[mt], bh, acc[mt][ct], 0, 0, 0);
                acc[mt][ct] = __builtin_amdgcn_mfma_f32_16x16x32_bf16(ah[mt], bl, acc[mt][ct], 0, 0, 0);
                acc[mt][ct] = __builtin_amdgcn_mfma_f32_16x16x32_bf16(al[mt], bh, acc[mt][ct], 0, 0, 0);
            }
        }
        __syncthreads();
    }
    // ---- epilogue (C layout: col=lane&15, row=quad*4+reg) ----
    #pragma unroll
    for (int ct = 0; ct < 8; ++ct) {
        const int col = wcol + ct * 16 + r16;
        const float bv = bias[col];
        #pragma unroll
        for (int mt = 0; mt < 4; ++mt) {
            const long rb = row0 + wrow + mt * 16 + quad * 4;
            f32x4 a = acc[mt][ct];
            if (isbf) {
                ushort* o = (ushort*)out;
                #pragma unroll
                for (int i = 0; i < 4; ++i) o[(rb + i) * DD + col] = f2b(a[i] + bv);
            } else {
                float* o = (float*)out;
                #pragma unroll
                for (int i = 0; i < 4; ++i) o[(rb + i) * DD + col] = a[i] + bv;
            }
        }
    }
}

// ======================= small MFMA GEMM (128-row global path; R2-proven) =======================
struct GemmPtrs {
    const float* X;
    const ushort* W0; const ushort* W1; const ushort* W2;
    const float* b0; const float* b1; const float* b2;
    void* o0; void* o1; void* o2;
    int bf16mask;
};

__global__ __launch_bounds__(256, 2) void gemm_small(GemmPtrs p)
{
    __shared__ __align__(16) short As[2][128][40];
    __shared__ __align__(16) short Bsm[2][256][40];
    const int tid = threadIdx.x;
    const int w = tid >> 6, lane = tid & 63;
    const int quad = lane >> 4, r16 = lane & 15;
    const long row0 = (long)blockIdx.x * 128;
    const int mat = blockIdx.y;
    const ushort* W = (mat == 0) ? p.W0 : (mat == 1 ? p.W1 : p.W2);
    const float* bias = (mat == 0) ? p.b0 : (mat == 1 ? p.b1 : p.b2);
    void* out = (mat == 0) ? p.o0 : (mat == 1 ? p.o1 : p.o2);
    const int isbf = (p.bf16mask >> mat) & 1;
    const int wrow = (w & 1) * 64;
    const int wcol = (w >> 1) * 128;

    f32x4 acc[4][8];
    #pragma unroll
    for (int rt = 0; rt < 4; ++rt)
        #pragma unroll
        for (int ct = 0; ct < 8; ++ct)
            acc[rt][ct] = (f32x4){0.f, 0.f, 0.f, 0.f};

    const int arow = tid >> 1;
    const int kb = (tid & 1) << 4;
    const float* abase = p.X + (row0 + arow) * DD + kb;
    const short* wb = (const short*)W + tid * DD;

    for (int kc = 0; kc < 8; ++kc) {
        __syncthreads();
        {
            const float* src = abase + kc * 32;
            #pragma unroll
            for (int gx = 0; gx < 2; ++gx) {
                float4 x0 = *(const float4*)(src + gx * 8);
                float4 x1 = *(const float4*)(src + gx * 8 + 4);
                float xs[8] = {x0.x, x0.y, x0.z, x0.w, x1.x, x1.y, x1.z, x1.w};
                short h[8], l[8];
                #pragma unroll
                for (int i = 0; i < 8; ++i) split2(xs[i], h[i], l[i]);
                *(short8*)&As[0][arow][kb + gx * 8] = (short8){h[0],h[1],h[2],h[3],h[4],h[5],h[6],h[7]};
                *(short8*)&As[1][arow][kb + gx * 8] = (short8){l[0],l[1],l[2],l[3],l[4],l[5],l[6],l[7]};
            }
        }
        {
            const short* srcH = wb + kc * 32;
            const short* srcL = srcH + 65536;
            #pragma unroll
            for (int gx = 0; gx < 4; ++gx) {
                *(short8*)&Bsm[0][tid][gx * 8] = *(const short8*)(srcH + gx * 8);
                *(short8*)&Bsm[1][tid][gx * 8] = *(const short8*)(srcL + gx * 8);
            }
        }
        __syncthreads();
        short8 af[4][2];
        #pragma unroll
        for (int rt = 0; rt < 4; ++rt) {
            const int rr = wrow + rt * 16 + r16;
            af[rt][0] = *(const short8*)&As[0][rr][quad * 8];
            af[rt][1] = *(const short8*)&As[1][rr][quad * 8];
        }
        #pragma unroll
        for (int ct = 0; ct < 8; ++ct) {
            const int cc = wcol + ct * 16 + r16;
            short8 bh = *(const short8*)&Bsm[0][cc][quad * 8];
            short8 bl = *(const short8*)&Bsm[1][cc][quad * 8];
            #pragma unroll
            for (int rt = 0; rt < 4; ++rt) {
                acc[rt][ct] = __builtin_amdgcn_mfma_f32_16x16x32_bf16(af[rt][0], bh, acc[rt][ct], 0, 0, 0);
                acc[rt][ct] = __builtin_amdgcn_mfma_f32_16x16x32_bf16(af[rt][0], bl, acc[rt][ct], 0, 0, 0);
                acc[rt][ct] = __builtin_amdgcn_mfma_f32_16x16x32_bf16(af[rt][1], bh, acc[rt][ct], 0, 0, 0);
            }
        }
    }
    #pragma unroll
    for (int ct = 0; ct < 8; ++ct) {
        const int col = wcol + ct * 16 + r16;
        const float bv = bias[col];
        #pragma unroll
        for (int rt = 0; rt < 4; ++rt) {
            const long rb = row0 + wrow + rt * 16 + quad * 4;
            f32x4 a = acc[rt][ct];
            if (isbf) {
                ushort* o = (ushort*)out;
                #pragma unroll
                for (int i = 0; i < 4; ++i) o[(rb + i) * DD + col] = f2b(a[i] + bv);
            } else {
                float* o = (float*)out;
                #pragma unroll
                for (int i = 0; i < 4; ++i) o[(rb + i) * DD + col] = a[i] + bv;
            }
        }
    }
}

// ======================= banded decay attention + fused GN partial stats =======================
__global__ __launch_bounds__(256) void attn(const float* __restrict__ Q, const ushort* __restrict__ K,
                                            const ushort* __restrict__ V, float* __restrict__ O,
                                            float* __restrict__ part)
{
    __shared__ __align__(16) float Kt[96][36];
    __shared__ __align__(16) float Vt[96][36];
    const int tid = threadIdx.x;
    const int rowIdx = tid >> 2;
    const int qq = tid & 3;
    const int t0 = blockIdx.y * 64;
    const long sbase = (long)blockIdx.x * 512;
    const int lrem = 512 - t0;
    const int ktrows = lrem < 96 ? lrem : 96;
    float sm = 0.f, ssum = 0.f;

    for (int h = 0; h < 8; ++h) {
        #pragma unroll
        for (int it = 0; it < 3; ++it) {
            int idx = tid + it * 256;
            int kr = idx >> 3, d4 = (idx & 7) << 2;
            if (kr < ktrows) {
                long gr = (sbase + t0 + kr) * DD + h * 32 + d4;
                ushort4 kv = *(const ushort4*)&K[gr];
                ushort4 vv = *(const ushort4*)&V[gr];
                *(float4*)&Kt[kr][d4] = make_float4(b2f(kv.x), b2f(kv.y), b2f(kv.z), b2f(kv.w));
                *(float4*)&Vt[kr][d4] = make_float4(b2f(vv.x), b2f(vv.y), b2f(vv.z), b2f(vv.w));
            }
        }
        __syncthreads();

        float qr[8];
        {
            long gq_ = (sbase + t0 + rowIdx) * DD + h * 32 + (qq << 3);
            float4 a = *(const float4*)&Q[gq_];
            float4 b = *(const float4*)&Q[gq_ + 4];
            qr[0] = a.x; qr[1] = a.y; qr[2] = a.z; qr[3] = a.w;
            qr[4] = b.x; qr[5] = b.y; qr[6] = b.z; qr[7] = b.w;
        }
        float o[8] = {0.f, 0.f, 0.f, 0.f, 0.f, 0.f, 0.f, 0.f};
        for (int dl = 0; dl < 32; ++dl) {
            int krow = rowIdx + dl;
            if (krow < ktrows) {
                const float* kp = &Kt[krow][qq << 3];
                float4 ka = *(const float4*)kp;
                float4 kb2 = *(const float4*)(kp + 4);
                float s = qr[0]*ka.x + qr[1]*ka.y + qr[2]*ka.z + qr[3]*ka.w
                        + qr[4]*kb2.x + qr[5]*kb2.y + qr[6]*kb2.z + qr[7]*kb2.w;
                s += __shfl_xor(s, 1, 64);
                s += __shfl_xor(s, 2, 64);
                s *= __expf(-(float)dl);
                const float* vp = &Vt[krow][qq << 3];
                float4 va = *(const float4*)vp;
                float4 vb = *(const float4*)(vp + 4);
                o[0] += s*va.x; o[1] += s*va.y; o[2] += s*va.z; o[3] += s*va.w;
                o[4] += s*vb.x; o[5] += s*vb.y; o[6] += s*vb.z; o[7] += s*vb.w;
            }
        }
        long go_ = (sbase + t0 + rowIdx) * DD + h * 32 + (qq << 3);
        *(float4*)&O[go_]     = make_float4(o[0], o[1], o[2], o[3]);
        *(float4*)&O[go_ + 4] = make_float4(o[4], o[5], o[6], o[7]);
        #pragma unroll
        for (int i = 0; i < 8; ++i) { sm += o[i]; ssum += o[i] * o[i]; }
        __syncthreads();
    }
    // block-level GN partial -> atomic
    #pragma unroll
    for (int off = 32; off > 0; off >>= 1) {
        sm   += __shfl_down(sm, off, 64);
        ssum += __shfl_down(ssum, off, 64);
    }
    __shared__ float red2[8];
    const int wv = tid >> 6;
    if ((tid & 63) == 0) { red2[wv] = sm; red2[4 + wv] = ssum; }
    __syncthreads();
    if (tid == 0) atomicAdd(&part[2 * blockIdx.x],     red2[0] + red2[1] + red2[2] + red2[3]);
    if (tid == 1) atomicAdd(&part[2 * blockIdx.x + 1], red2[4] + red2[5] + red2[6] + red2[7]);
}

// ======================= small dense attention (N=32) =======================
__global__ __launch_bounds__(64) void small_attn(const float* __restrict__ Q, const ushort* __restrict__ K,
                                                 const ushort* __restrict__ V, float* __restrict__ O)
{
    int b = blockIdx.x >> 3, h = blockIdx.x & 7;
    int i = threadIdx.x;
    if (i >= 32) return;
    long base = (long)b * 32 * DD + h * 32;
    float qr[32], o[32];
    #pragma unroll
    for (int d4 = 0; d4 < 8; ++d4) {
        float4 t = *(const float4*)&Q[base + (long)i * DD + d4 * 4];
        qr[d4*4+0] = t.x; qr[d4*4+1] = t.y; qr[d4*4+2] = t.z; qr[d4*4+3] = t.w;
    }
    #pragma unroll
    for (int d = 0; d < 32; ++d) o[d] = 0.f;
    for (int j = i; j < 32; ++j) {
        float s = 0.f;
        #pragma unroll
        for (int d4 = 0; d4 < 8; ++d4) {
            ushort4 kv = *(const ushort4*)&K[base + (long)j * DD + d4 * 4];
            s += qr[d4*4+0]*b2f(kv.x) + qr[d4*4+1]*b2f(kv.y) + qr[d4*4+2]*b2f(kv.z) + qr[d4*4+3]*b2f(kv.w);
        }
        s *= __expf(-(float)(j - i));
        #pragma unroll
        for (int d4 = 0; d4 < 8; ++d4) {
            ushort4 vv = *(const ushort4*)&V[base + (long)j * DD + d4 * 4];
            o[d4*4+0] += s*b2f(vv.x); o[d4*4+1] += s*b2f(vv.y); o[d4*4+2] += s*b2f(vv.z); o[d4*4+3] += s*b2f(vv.w);
        }
    }
    #pragma unroll
    for (int d4 = 0; d4 < 8; ++d4)
        *(float4*)&O[base + (long)i * DD + d4 * 4] = make_float4(o[d4*4+0], o[d4*4+1], o[d4*4+2], o[d4*4+3]);
}

// ======================= GN helpers =======================
__global__ __launch_bounds__(256) void gnzero(float* __restrict__ part)
{
    part[threadIdx.x] = 0.f;
}

__global__ __launch_bounds__(256) void gn_stats(const float* __restrict__ buf, float2* __restrict__ part, int rpb)
{
    const int s = blockIdx.x;
    const long base = (long)s * rpb * DD;
    const float4* p = (const float4*)(buf + base);
    const int nf4 = rpb * 64;
    float sm = 0.f, ss = 0.f;
    for (int i = threadIdx.x; i < nf4; i += 256) {
        float4 v = p[i];
        sm += v.x + v.y + v.z + v.w;
        ss += v.x*v.x + v.y*v.y + v.z*v.z + v.w*v.w;
    }
    #pragma unroll
    for (int off = 32; off > 0; off >>= 1) {
        sm += __shfl_down(sm, off, 64);
        ss += __shfl_down(ss, off, 64);
    }
    __shared__ float rs[4], rss[4];
    if ((threadIdx.x & 63) == 0) { rs[threadIdx.x >> 6] = sm; rss[threadIdx.x >> 6] = ss; }
    __syncthreads();
    if (threadIdx.x == 0)
        part[s] = make_float2(rs[0]+rs[1]+rs[2]+rs[3], rss[0]+rss[1]+rss[2]+rss[3]);
}

__global__ __launch_bounds__(256) void gn_final(float* __restrict__ part, float2* __restrict__ stats,
                                                int ng, float invN)
{
    int t = threadIdx.x;
    if (t < ng) {
        float sm = part[2*t], ss = part[2*t+1];
        float mean = sm * invN;
        float var = ss * invN - mean * mean;
        stats[t] = make_float2(mean, rsqrtf(var + 1e-5f));
        part[2*t] = 0.f; part[2*t+1] = 0.f;
    }
}

__global__ __launch_bounds__(256) void gn_apply(float* __restrict__ buf, const float2* __restrict__ stats,
                                                const float* __restrict__ w, const float* __restrict__ b, int shift)
{
    long i = (long)blockIdx.x * 256 + threadIdx.x;
    long e = i * 4;
    int seq = (int)(e >> shift);
    int d0 = (int)(e & 255);
    float2 st = stats[seq];
    float4 v = ((const float4*)buf)[i];
    float4 wv = *(const float4*)&w[d0];
    float4 bv = *(const float4*)&b[d0];
    v.x = (v.x - st.x) * st.y * wv.x + bv.x;
    v.y = (v.y - st.x) * st.y * wv.y + bv.y;
    v.z = (v.z - st.x) * st.y * wv.z + bv.z;
    v.w = (v.w - st.x) * st.y * wv.w + bv.w;
    ((float4*)buf)[i] = v;
}

// ======================= softmax-pool =======================
// big path: bf16 gate pre-activations + raw X + fused GN
__global__ __launch_bounds__(256) void pool_partial_big(const ushort* __restrict__ AW, const ushort* __restrict__ AU,
                                                        const float* __restrict__ X, const float2* __restrict__ stats,
                                                        const float* __restrict__ gnw, const float* __restrict__ gnb,
                                                        const float* __restrict__ g,
                                                        float* __restrict__ part, int rpb)
{
    const int s = blockIdx.x, ch = blockIdx.y, NC = gridDim.y, d = threadIdx.x;
    const long rowbase = ((long)s * NC + ch) * rpb;
    const float g0 = g[0];
    const float2 st = stats[s];
    const float wd = gnw[d], bd = gnb[d];
    float l = 0.f, acc = 0.f;
    for (int j = 0; j < rpb; ++j) {
        long idx = (rowbase + j) * DD + d;
        float aw = b2f(AW[idx]);
        float au = b2f(AU[idx]);
        float x = (X[idx] - st.x) * st.y * wd + bd;
        float a = g0 * tanhf(aw) * (1.f / (1.f + __expf(-au)));
        float e = __expf(a);
        l += e; acc += e * x;
    }
    long pbase = (long)(s * NC + ch) * 512;
    part[pbase + d] = l;
    part[pbase + 256 + d] = acc;
}

// small path: fp32 gates, pre-normalized X
__global__ __launch_bounds__(256) void pool_partial_small(const float* __restrict__ AW, const float* __restrict__ AU,
                                                          const float* __restrict__ X, const float* __restrict__ g,
                                                          float* __restrict__ part, int rpb)
{
    const int s = blockIdx.x, d = threadIdx.x;
    const long rowbase = (long)s * rpb;
    const float g0 = g[0];
    float l = 0.f, acc = 0.f;
    for (int j = 0; j < rpb; ++j) {
        long idx = (rowbase + j) * DD + d;
        float a = g0 * tanhf(AW[idx]) * (1.f / (1.f + __expf(-AU[idx])));
        float e = __expf(a);
        l += e; acc += e * X[idx];
    }
    long pbase = (long)s * 512;
    part[pbase + d] = l;
    part[pbase + 256 + d] = acc;
}

__global__ __launch_bounds__(256) void pool_final(const float* __restrict__ part, float* __restrict__ out, int NC)
{
    const int s = blockIdx.x, d = threadIdx.x;
    float l = 0.f, acc = 0.f;
    for (int c = 0; c < NC; ++c) {
        long pbase = (long)(s * NC + c) * 512;
        l += part[pbase + d];
        acc += part[pbase + 256 + d];
    }
    out[(long)s * DD + d] = acc / l;
}

// ======================= BatchNorm + classifier =======================
__global__ __launch_bounds__(256) void bn_cls(const float* __restrict__ emb, const float* __restrict__ bn_w,
                                              const float* __restrict__ bn_b, const float* __restrict__ cls_W,
                                              const float* __restrict__ cls_b, float* __restrict__ out)
{
    int d = threadIdx.x;
    float e0 = emb[d], e1 = emb[256 + d], e2 = emb[512 + d], e3 = emb[768 + d];
    float mu = 0.25f * (e0 + e1 + e2 + e3);
    float v0 = e0 - mu, v1 = e1 - mu, v2 = e2 - mu, v3 = e3 - mu;
    float var = 0.25f * (v0*v0 + v1*v1 + v2*v2 + v3*v3);
    float rs = rsqrtf(var + 1e-5f);
    float w = bn_w[d], bb = bn_b[d];
    float z0 = v0*rs*w + bb, z1 = v1*rs*w + bb, z2 = v2*rs*w + bb, z3 = v3*rs*w + bb;
    float w0 = cls_W[d], w1 = cls_W[256 + d];
    __shared__ float red[8][256];
    red[0][d] = z0*w0; red[1][d] = z0*w1;
    red[2][d] = z1*w0; red[3][d] = z1*w1;
    red[4][d] = z2*w0; red[5][d] = z2*w1;
    red[6][d] = z3*w0; red[7][d] = z3*w1;
    __syncthreads();
    for (int off = 128; off > 0; off >>= 1) {
        if (d < off) {
            #pragma unroll
            for (int m = 0; m < 8; ++m) red[m][d] += red[m][d + off];
        }
        __syncthreads();
    }
    if (d < 8) out[d] = red[d][0] + cls_b[d & 1];
}

// ======================= host =======================
extern "C" void kernel_launch(void* const* d_in, const int* in_sizes, int n_in,
                              void* d_out, int out_size, void* d_ws, size_t ws_size,
                              hipStream_t stream)
{
    (void)in_sizes; (void)n_in; (void)out_size;
#define F(i) ((const float*)d_in[i])
    const float* bags = F(0);

    const size_t smallF = 1600000;
    int nch = 1;
    while (nch < 128) {
        size_t bigF_ = ((size_t)(128 / nch)) * 512 * 256;
        if ((3 * bigF_ + smallF) * 4 <= ws_size) break;
        nch <<= 1;
    }
    const int cseq = 128 / nch;
    const size_t crows = (size_t)cseq * 512;
    const size_t bigF = crows * 256;

    float* Xb  = (float*)d_ws;                 // attn output / gemm input (raw fp32)
    float* Qb  = Xb + bigF;                    // Q fp32; pool AW region start too
    float* KVb = Xb + 2 * bigF;                // K,V bf16 halves; later AW,AU bf16
    ushort* Kb = (ushort*)KVb;
    ushort* Vb = Kb + crows * 256;
    float* sm = Xb + 3 * bigF;
    ushort* Wbig = (ushort*)sm;                // 8 mats x 131072 shorts (frag order)
    ushort* Wsm  = Wbig + 8 * 131072;          // 5 mats x 131072 shorts (old order)
    float* after = sm + 524288 + 327680;
    float* local_ = after;                     // 128*256
    float* gq   = local_ + 32768;
    float* gkv  = gq + 32768;
    ushort* gkb = (ushort*)gkv;
    ushort* gvb = gkb + 32768;
    float* go   = gkv + 32768;
    float* AWg  = go + 32768;
    float* AUg  = AWg + 32768;
    float* embb = AUg + 32768;                 // 1024
    float* gnpart = embb + 1024;               // 256 floats (128 x float2)
    float2* gnstats = (float2*)(gnpart + 256); // 128 x float2
    float* ppart = gnpart + 512;               // [1024][512] max

    // --- weight conversion ---
    WPtrs8 wb8; const int bigidx[8] = {1, 3, 5, 9, 11, 13, 25, 27};
    for (int i = 0; i < 8; ++i) wb8.w[i] = F(bigidx[i]);
    wcvt_frag<<<512, 256, 0, stream>>>(wb8, Wbig);
    WPtrs5 ws5; const int smidx[5] = {17, 19, 21, 30, 32};
    for (int i = 0; i < 5; ++i) ws5.w[i] = F(smidx[i]);
    wcvt_old<<<320, 256, 0, stream>>>(ws5, Wsm);
    gnzero<<<1, 256, 0, stream>>>(gnpart);

    dim3 blk(256);
    const int gx = (int)(crows / 128);
    const float invBig = 1.f / 131072.f;

    for (int c = 0; c < nch; ++c) {
        const float* xin = bags + (size_t)c * bigF;
        // retention 1
        GemmBig g1 = {xin, nullptr, nullptr, nullptr, Wbig,
                      F(2), F(4), F(6), Qb, Kb, Vb, 0b110};
        gemm_big<<<dim3(gx, 3), blk, 0, stream>>>(g1);
        attn<<<dim3(cseq, 8), blk, 0, stream>>>(Qb, Kb, Vb, Xb, gnpart);
        gn_final<<<1, blk, 0, stream>>>(gnpart, gnstats, cseq, invBig);
        // retention 2 (GN of layer1 fused into A-load)
        GemmBig g2 = {Xb, gnstats, F(7), F(8), Wbig + 3 * 131072,
                      F(10), F(12), F(14), Qb, Kb, Vb, 0b110};
        gemm_big<<<dim3(gx, 3), blk, 0, stream>>>(g2);
        attn<<<dim3(cseq, 8), blk, 0, stream>>>(Qb, Kb, Vb, Xb, gnpart);
        gn_final<<<1, blk, 0, stream>>>(gnpart, gnstats, cseq, invBig);
        // local pool (GN of layer2 fused into A-load; gates out bf16)
        GemmBig gp = {Xb, gnstats, F(15), F(16), Wbig + 6 * 131072,
                      F(26), F(28), nullptr, Kb, Vb, nullptr, 0b11};
        gemm_big<<<dim3(gx, 2), blk, 0, stream>>>(gp);
        pool_partial_big<<<dim3(cseq, 8), blk, 0, stream>>>(Kb, Vb, Xb, gnstats, F(15), F(16), F(29), ppart, 64);
        pool_final<<<cseq, blk, 0, stream>>>(ppart, local_ + (size_t)c * cseq * 256, 8);
    }

    // global retention on local [4 x 32 x 256] = 128 rows
    GemmPtrs gg = {local_, Wsm, Wsm + 131072, Wsm + 2 * 131072,
                   F(18), F(20), F(22), gq, gkb, gvb, 0b110};
    gemm_small<<<dim3(1, 3), blk, 0, stream>>>(gg);
    small_attn<<<32, 64, 0, stream>>>(gq, gkb, gvb, go);
    gn_stats<<<4, blk, 0, stream>>>(go, (float2*)gnpart, 32);
    gn_final<<<1, blk, 0, stream>>>(gnpart, gnstats, 4, 1.f / 8192.f);
    gn_apply<<<32, blk, 0, stream>>>(go, gnstats, F(23), F(24), 13);

    GemmPtrs gpg = {go, Wsm + 3 * 131072, Wsm + 4 * 131072, nullptr,
                    F(31), F(33), nullptr, AWg, AUg, nullptr, 0};
    gemm_small<<<dim3(1, 2), blk, 0, stream>>>(gpg);
    pool_partial_small<<<4, blk, 0, stream>>>(AWg, AUg, go, F(34), ppart, 32);
    pool_final<<<4, blk, 0, stream>>>(ppart, embb, 1);

    bn_cls<<<1, blk, 0, stream>>>(embb, F(35), F(36), F(37), F(38), (float*)d_out);
#undef F
}

// Round 4
// 796.657 us; speedup vs baseline: 2.8895x; 1.0338x over previous
//
#include <hip/hip_runtime.h>

typedef unsigned int uint;
typedef unsigned short ushort;
typedef __attribute__((ext_vector_type(8))) short short8;
typedef __attribute__((ext_vector_type(4))) float f32x4;

#define DD 256

__device__ __forceinline__ float b2f(ushort u) {
    return __uint_as_float(((uint)u) << 16);
}
__device__ __forceinline__ ushort f2b(float f) {
    uint u = __float_as_uint(f);
    u += 0x7FFFu + ((u >> 16) & 1u);
    return (ushort)(u >> 16);
}
__device__ __forceinline__ void split2(float x, short& h, short& l) {
    uint u = __float_as_uint(x);
    uint hr = (u + 0x7FFFu + ((u >> 16) & 1u)) & 0xFFFF0000u;
    h = (short)(hr >> 16);
    l = (short)(__float_as_uint(x - __uint_as_float(hr)) >> 16);
}

// ======================= weight pre-split, row-major hi/lo (small path, split3) =======================
struct WPtrs5 { const float* w[5]; };

__global__ __launch_bounds__(256) void wcvt_old(WPtrs5 p, ushort* __restrict__ out)
{
    int idx = blockIdx.x * 256 + threadIdx.x;    // float4 index; 5*16384 total
    int mat = idx >> 14;
    int off = idx & 16383;
    float4 v = *((const float4*)p.w[mat] + off);
    float xs[4] = {v.x, v.y, v.z, v.w};
    ushort h[4], l[4];
    #pragma unroll
    for (int i = 0; i < 4; ++i) {
        short hh, ll;
        split2(xs[i], hh, ll);
        h[i] = (ushort)hh; l[i] = (ushort)ll;
    }
    *((ushort4*)(out + (size_t)mat * 131072) + off) = make_ushort4(h[0], h[1], h[2], h[3]);
    *((ushort4*)(out + (size_t)mat * 131072 + 65536) + off) = make_ushort4(l[0], l[1], l[2], l[3]);
}

// ======================= weight bf16 round, MFMA-fragment order (big path) =======================
// layout: [mat][kc8][nt16][lane64][8]; lane holds W[n=nt*16+(lane&15)][k=kc*32+(lane>>4)*8 + j]
struct WPtrs8 { const float* w[8]; };

__global__ __launch_bounds__(256) void wcvt_frag(WPtrs8 p, ushort* __restrict__ out)
{
    int idx = blockIdx.x * 256 + threadIdx.x;    // short8 index; 8*8*16*64 = 65536 total
    int lane = idx & 63;
    int nt = (idx >> 6) & 15;
    int kc = (idx >> 10) & 7;
    int mat = idx >> 13;
    int n = nt * 16 + (lane & 15);
    int k = kc * 32 + (lane >> 4) * 8;
    const float* src = p.w[mat] + n * DD + k;
    float4 x0 = *(const float4*)src;
    float4 x1 = *(const float4*)(src + 4);
    float xs[8] = {x0.x, x0.y, x0.z, x0.w, x1.x, x1.y, x1.z, x1.w};
    short o8[8];
    #pragma unroll
    for (int i = 0; i < 8; ++i) o8[i] = (short)f2b(xs[i]);
    *(short8*)(out + (size_t)idx * 8) = (short8){o8[0],o8[1],o8[2],o8[3],o8[4],o8[5],o8[6],o8[7]};
}

// ======================= big MFMA GEMM: bf16-only, LDS-A (one barrier), global-frag B =======================
struct GemmBig {
    const float* X;            // raw rows [R][256] fp32
    const float2* stats;       // per-seq (mean, rsig) or nullptr
    const float* gnw; const float* gnb;
    const ushort* W;           // fragment-ordered bf16, mats consecutive (65536 shorts each)
    const float* b0; const float* b1; const float* b2;
    void* o0; void* o1; void* o2;
    int bf16mask;
};

__global__ __launch_bounds__(256, 2) void gemm_big(GemmBig p)
{
    __shared__ __align__(16) ushort As[128][264];   // +8 pad: conflict-free b128 frag reads
    const int tid = threadIdx.x, w = tid >> 6, lane = tid & 63;
    const int quad = lane >> 4, r16 = lane & 15;
    const long row0 = (long)blockIdx.x * 128;
    const int mat = blockIdx.y;
    const ushort* Wm = p.W + (size_t)mat * 65536;
    const float* bias = (mat == 0) ? p.b0 : (mat == 1 ? p.b1 : p.b2);
    void* out = (mat == 0) ? p.o0 : (mat == 1 ? p.o1 : p.o2);
    const int isbf = (p.bf16mask >> mat) & 1;
    const int wrow = (w & 1) * 64, wcol = (w >> 1) * 128;
    const bool gn = (p.stats != nullptr);

    // all 128 rows of this block share one sequence (block row-span 128 < 512)
    float mu = 0.f, rsg = 1.f;
    if (gn) { float2 st = p.stats[row0 >> 9]; mu = st.x; rsg = st.y; }

    // ---- stage entire A tile to LDS: thread -> row=tid>>1, k-half=(tid&1)*128 ----
    {
        const int arow = tid >> 1;
        const int kh = (tid & 1) * 128;
        const float* src = p.X + (row0 + arow) * DD + kh;
        #pragma unroll
        for (int i = 0; i < 8; ++i) {
            float4 x0 = *(const float4*)(src + i * 16);
            float4 x1 = *(const float4*)(src + i * 16 + 4);
            float4 x2 = *(const float4*)(src + i * 16 + 8);
            float4 x3 = *(const float4*)(src + i * 16 + 12);
            float xs[16] = {x0.x,x0.y,x0.z,x0.w, x1.x,x1.y,x1.z,x1.w,
                            x2.x,x2.y,x2.z,x2.w, x3.x,x3.y,x3.z,x3.w};
            if (gn) {
                const float* gwp = p.gnw + kh + i * 16;
                const float* gbp = p.gnb + kh + i * 16;
                #pragma unroll
                for (int j = 0; j < 16; ++j)
                    xs[j] = (xs[j] - mu) * rsg * gwp[j] + gbp[j];
            }
            short o16[16];
            #pragma unroll
            for (int j = 0; j < 16; ++j) o16[j] = (short)f2b(xs[j]);
            *(short8*)&As[arow][kh + i * 16]     = (short8){o16[0],o16[1],o16[2],o16[3],o16[4],o16[5],o16[6],o16[7]};
            *(short8*)&As[arow][kh + i * 16 + 8] = (short8){o16[8],o16[9],o16[10],o16[11],o16[12],o16[13],o16[14],o16[15]};
        }
    }
    __syncthreads();     // the ONLY barrier

    f32x4 acc[4][8];
    #pragma unroll
    for (int mt = 0; mt < 4; ++mt)
        #pragma unroll
        for (int ct = 0; ct < 8; ++ct)
            acc[mt][ct] = (f32x4){0.f, 0.f, 0.f, 0.f};

    const int nt0 = wcol >> 4;
    #pragma unroll 2
    for (int kc = 0; kc < 8; ++kc) {
        short8 bfr[8];
        #pragma unroll
        for (int ct = 0; ct < 8; ++ct)
            bfr[ct] = *(const short8*)(Wm + (((kc * 16 + nt0 + ct) << 9) + lane * 8));
        short8 af[4];
        #pragma unroll
        for (int mt = 0; mt < 4; ++mt)
            af[mt] = *(const short8*)&As[wrow + mt * 16 + r16][kc * 32 + quad * 8];
        #pragma unroll
        for (int ct = 0; ct < 8; ++ct)
            #pragma unroll
            for (int mt = 0; mt < 4; ++mt)
                acc[mt][ct] = __builtin_amdgcn_mfma_f32_16x16x32_bf16(af[mt], bfr[ct], acc[mt][ct], 0, 0, 0);
    }

    // ---- epilogue (C layout: col=lane&15, row=quad*4+reg) ----
    #pragma unroll
    for (int ct = 0; ct < 8; ++ct) {
        const int col = wcol + ct * 16 + r16;
        const float bv = bias[col];
        #pragma unroll
        for (int mt = 0; mt < 4; ++mt) {
            const long rb = row0 + wrow + mt * 16 + quad * 4;
            f32x4 a = acc[mt][ct];
            if (isbf) {
                ushort* o = (ushort*)out;
                #pragma unroll
                for (int i = 0; i < 4; ++i) o[(rb + i) * DD + col] = f2b(a[i] + bv);
            } else {
                float* o = (float*)out;
                #pragma unroll
                for (int i = 0; i < 4; ++i) o[(rb + i) * DD + col] = a[i] + bv;
            }
        }
    }
}

// ======================= small MFMA GEMM (128-row global path; split3, proven) =======================
struct GemmPtrs {
    const float* X;
    const ushort* W0; const ushort* W1; const ushort* W2;
    const float* b0; const float* b1; const float* b2;
    void* o0; void* o1; void* o2;
    int bf16mask;
};

__global__ __launch_bounds__(256, 2) void gemm_small(GemmPtrs p)
{
    __shared__ __align__(16) short As[2][128][40];
    __shared__ __align__(16) short Bsm[2][256][40];
    const int tid = threadIdx.x;
    const int w = tid >> 6, lane = tid & 63;
    const int quad = lane >> 4, r16 = lane & 15;
    const long row0 = (long)blockIdx.x * 128;
    const int mat = blockIdx.y;
    const ushort* W = (mat == 0) ? p.W0 : (mat == 1 ? p.W1 : p.W2);
    const float* bias = (mat == 0) ? p.b0 : (mat == 1 ? p.b1 : p.b2);
    void* out = (mat == 0) ? p.o0 : (mat == 1 ? p.o1 : p.o2);
    const int isbf = (p.bf16mask >> mat) & 1;
    const int wrow = (w & 1) * 64;
    const int wcol = (w >> 1) * 128;

    f32x4 acc[4][8];
    #pragma unroll
    for (int rt = 0; rt < 4; ++rt)
        #pragma unroll
        for (int ct = 0; ct < 8; ++ct)
            acc[rt][ct] = (f32x4){0.f, 0.f, 0.f, 0.f};

    const int arow = tid >> 1;
    const int kb = (tid & 1) << 4;
    const float* abase = p.X + (row0 + arow) * DD + kb;
    const short* wb = (const short*)W + tid * DD;

    for (int kc = 0; kc < 8; ++kc) {
        __syncthreads();
        {
            const float* src = abase + kc * 32;
            #pragma unroll
            for (int gx = 0; gx < 2; ++gx) {
                float4 x0 = *(const float4*)(src + gx * 8);
                float4 x1 = *(const float4*)(src + gx * 8 + 4);
                float xs[8] = {x0.x, x0.y, x0.z, x0.w, x1.x, x1.y, x1.z, x1.w};
                short h[8], l[8];
                #pragma unroll
                for (int i = 0; i < 8; ++i) split2(xs[i], h[i], l[i]);
                *(short8*)&As[0][arow][kb + gx * 8] = (short8){h[0],h[1],h[2],h[3],h[4],h[5],h[6],h[7]};
                *(short8*)&As[1][arow][kb + gx * 8] = (short8){l[0],l[1],l[2],l[3],l[4],l[5],l[6],l[7]};
            }
        }
        {
            const short* srcH = wb + kc * 32;
            const short* srcL = srcH + 65536;
            #pragma unroll
            for (int gx = 0; gx < 4; ++gx) {
                *(short8*)&Bsm[0][tid][gx * 8] = *(const short8*)(srcH + gx * 8);
                *(short8*)&Bsm[1][tid][gx * 8] = *(const short8*)(srcL + gx * 8);
            }
        }
        __syncthreads();
        short8 af[4][2];
        #pragma unroll
        for (int rt = 0; rt < 4; ++rt) {
            const int rr = wrow + rt * 16 + r16;
            af[rt][0] = *(const short8*)&As[0][rr][quad * 8];
            af[rt][1] = *(const short8*)&As[1][rr][quad * 8];
        }
        #pragma unroll
        for (int ct = 0; ct < 8; ++ct) {
            const int cc = wcol + ct * 16 + r16;
            short8 bh = *(const short8*)&Bsm[0][cc][quad * 8];
            short8 bl = *(const short8*)&Bsm[1][cc][quad * 8];
            #pragma unroll
            for (int rt = 0; rt < 4; ++rt) {
                acc[rt][ct] = __builtin_amdgcn_mfma_f32_16x16x32_bf16(af[rt][0], bh, acc[rt][ct], 0, 0, 0);
                acc[rt][ct] = __builtin_amdgcn_mfma_f32_16x16x32_bf16(af[rt][0], bl, acc[rt][ct], 0, 0, 0);
                acc[rt][ct] = __builtin_amdgcn_mfma_f32_16x16x32_bf16(af[rt][1], bh, acc[rt][ct], 0, 0, 0);
            }
        }
    }
    #pragma unroll
    for (int ct = 0; ct < 8; ++ct) {
        const int col = wcol + ct * 16 + r16;
        const float bv = bias[col];
        #pragma unroll
        for (int rt = 0; rt < 4; ++rt) {
            const long rb = row0 + wrow + rt * 16 + quad * 4;
            f32x4 a = acc[rt][ct];
            if (isbf) {
                ushort* o = (ushort*)out;
                #pragma unroll
                for (int i = 0; i < 4; ++i) o[(rb + i) * DD + col] = f2b(a[i] + bv);
            } else {
                float* o = (float*)out;
                #pragma unroll
                for (int i = 0; i < 4; ++i) o[(rb + i) * DD + col] = a[i] + bv;
            }
        }
    }
}

// ======================= banded decay attention + fused GN partial stats =======================
__global__ __launch_bounds__(256) void attn(const float* __restrict__ Q, const ushort* __restrict__ K,
                                            const ushort* __restrict__ V, float* __restrict__ O,
                                            float* __restrict__ part)
{
    __shared__ __align__(16) float Kt[96][36];
    __shared__ __align__(16) float Vt[96][36];
    const int tid = threadIdx.x;
    const int rowIdx = tid >> 2;
    const int qq = tid & 3;
    const int t0 = blockIdx.y * 64;
    const long sbase = (long)blockIdx.x * 512;
    const int lrem = 512 - t0;
    const int ktrows = lrem < 96 ? lrem : 96;
    float sm = 0.f, ssum = 0.f;

    for (int h = 0; h < 8; ++h) {
        #pragma unroll
        for (int it = 0; it < 3; ++it) {
            int idx = tid + it * 256;
            int kr = idx >> 3, d4 = (idx & 7) << 2;
            if (kr < ktrows) {
                long gr = (sbase + t0 + kr) * DD + h * 32 + d4;
                ushort4 kv = *(const ushort4*)&K[gr];
                ushort4 vv = *(const ushort4*)&V[gr];
                *(float4*)&Kt[kr][d4] = make_float4(b2f(kv.x), b2f(kv.y), b2f(kv.z), b2f(kv.w));
                *(float4*)&Vt[kr][d4] = make_float4(b2f(vv.x), b2f(vv.y), b2f(vv.z), b2f(vv.w));
            }
        }
        __syncthreads();

        float qr[8];
        {
            long gq_ = (sbase + t0 + rowIdx) * DD + h * 32 + (qq << 3);
            float4 a = *(const float4*)&Q[gq_];
            float4 b = *(const float4*)&Q[gq_ + 4];
            qr[0] = a.x; qr[1] = a.y; qr[2] = a.z; qr[3] = a.w;
            qr[4] = b.x; qr[5] = b.y; qr[6] = b.z; qr[7] = b.w;
        }
        float o[8] = {0.f, 0.f, 0.f, 0.f, 0.f, 0.f, 0.f, 0.f};
        for (int dl = 0; dl < 32; ++dl) {
            int krow = rowIdx + dl;
            if (krow < ktrows) {
                const float* kp = &Kt[krow][qq << 3];
                float4 ka = *(const float4*)kp;
                float4 kb2 = *(const float4*)(kp + 4);
                float s = qr[0]*ka.x + qr[1]*ka.y + qr[2]*ka.z + qr[3]*ka.w
                        + qr[4]*kb2.x + qr[5]*kb2.y + qr[6]*kb2.z + qr[7]*kb2.w;
                s += __shfl_xor(s, 1, 64);
                s += __shfl_xor(s, 2, 64);
                s *= __expf(-(float)dl);
                const float* vp = &Vt[krow][qq << 3];
                float4 va = *(const float4*)vp;
                float4 vb = *(const float4*)(vp + 4);
                o[0] += s*va.x; o[1] += s*va.y; o[2] += s*va.z; o[3] += s*va.w;
                o[4] += s*vb.x; o[5] += s*vb.y; o[6] += s*vb.z; o[7] += s*vb.w;
            }
        }
        long go_ = (sbase + t0 + rowIdx) * DD + h * 32 + (qq << 3);
        *(float4*)&O[go_]     = make_float4(o[0], o[1], o[2], o[3]);
        *(float4*)&O[go_ + 4] = make_float4(o[4], o[5], o[6], o[7]);
        #pragma unroll
        for (int i = 0; i < 8; ++i) { sm += o[i]; ssum += o[i] * o[i]; }
        __syncthreads();
    }
    #pragma unroll
    for (int off = 32; off > 0; off >>= 1) {
        sm   += __shfl_down(sm, off, 64);
        ssum += __shfl_down(ssum, off, 64);
    }
    __shared__ float red2[8];
    const int wv = tid >> 6;
    if ((tid & 63) == 0) { red2[wv] = sm; red2[4 + wv] = ssum; }
    __syncthreads();
    if (tid == 0) atomicAdd(&part[2 * blockIdx.x],     red2[0] + red2[1] + red2[2] + red2[3]);
    if (tid == 1) atomicAdd(&part[2 * blockIdx.x + 1], red2[4] + red2[5] + red2[6] + red2[7]);
}

// ======================= small dense attention (N=32) =======================
__global__ __launch_bounds__(64) void small_attn(const float* __restrict__ Q, const ushort* __restrict__ K,
                                                 const ushort* __restrict__ V, float* __restrict__ O)
{
    int b = blockIdx.x >> 3, h = blockIdx.x & 7;
    int i = threadIdx.x;
    if (i >= 32) return;
    long base = (long)b * 32 * DD + h * 32;
    float qr[32], o[32];
    #pragma unroll
    for (int d4 = 0; d4 < 8; ++d4) {
        float4 t = *(const float4*)&Q[base + (long)i * DD + d4 * 4];
        qr[d4*4+0] = t.x; qr[d4*4+1] = t.y; qr[d4*4+2] = t.z; qr[d4*4+3] = t.w;
    }
    #pragma unroll
    for (int d = 0; d < 32; ++d) o[d] = 0.f;
    for (int j = i; j < 32; ++j) {
        float s = 0.f;
        #pragma unroll
        for (int d4 = 0; d4 < 8; ++d4) {
            ushort4 kv = *(const ushort4*)&K[base + (long)j * DD + d4 * 4];
            s += qr[d4*4+0]*b2f(kv.x) + qr[d4*4+1]*b2f(kv.y) + qr[d4*4+2]*b2f(kv.z) + qr[d4*4+3]*b2f(kv.w);
        }
        s *= __expf(-(float)(j - i));
        #pragma unroll
        for (int d4 = 0; d4 < 8; ++d4) {
            ushort4 vv = *(const ushort4*)&V[base + (long)j * DD + d4 * 4];
            o[d4*4+0] += s*b2f(vv.x); o[d4*4+1] += s*b2f(vv.y); o[d4*4+2] += s*b2f(vv.z); o[d4*4+3] += s*b2f(vv.w);
        }
    }
    #pragma unroll
    for (int d4 = 0; d4 < 8; ++d4)
        *(float4*)&O[base + (long)i * DD + d4 * 4] = make_float4(o[d4*4+0], o[d4*4+1], o[d4*4+2], o[d4*4+3]);
}

// ======================= GN helpers =======================
__global__ __launch_bounds__(256) void gnzero(float* __restrict__ part)
{
    part[threadIdx.x] = 0.f;
}

__global__ __launch_bounds__(256) void gn_stats(const float* __restrict__ buf, float2* __restrict__ part, int rpb)
{
    const int s = blockIdx.x;
    const long base = (long)s * rpb * DD;
    const float4* p = (const float4*)(buf + base);
    const int nf4 = rpb * 64;
    float sm = 0.f, ss = 0.f;
    for (int i = threadIdx.x; i < nf4; i += 256) {
        float4 v = p[i];
        sm += v.x + v.y + v.z + v.w;
        ss += v.x*v.x + v.y*v.y + v.z*v.z + v.w*v.w;
    }
    #pragma unroll
    for (int off = 32; off > 0; off >>= 1) {
        sm += __shfl_down(sm, off, 64);
        ss += __shfl_down(ss, off, 64);
    }
    __shared__ float rs[4], rss[4];
    if ((threadIdx.x & 63) == 0) { rs[threadIdx.x >> 6] = sm; rss[threadIdx.x >> 6] = ss; }
    __syncthreads();
    if (threadIdx.x == 0)
        part[s] = make_float2(rs[0]+rs[1]+rs[2]+rs[3], rss[0]+rss[1]+rss[2]+rss[3]);
}

__global__ __launch_bounds__(256) void gn_final(float* __restrict__ part, float2* __restrict__ stats,
                                                int ng, float invN)
{
    int t = threadIdx.x;
    if (t < ng) {
        float sm = part[2*t], ss = part[2*t+1];
        float mean = sm * invN;
        float var = ss * invN - mean * mean;
        stats[t] = make_float2(mean, rsqrtf(var + 1e-5f));
        part[2*t] = 0.f; part[2*t+1] = 0.f;
    }
}

__global__ __launch_bounds__(256) void gn_apply(float* __restrict__ buf, const float2* __restrict__ stats,
                                                const float* __restrict__ w, const float* __restrict__ b, int shift)
{
    long i = (long)blockIdx.x * 256 + threadIdx.x;
    long e = i * 4;
    int seq = (int)(e >> shift);
    int d0 = (int)(e & 255);
    float2 st = stats[seq];
    float4 v = ((const float4*)buf)[i];
    float4 wv = *(const float4*)&w[d0];
    float4 bv = *(const float4*)&b[d0];
    v.x = (v.x - st.x) * st.y * wv.x + bv.x;
    v.y = (v.y - st.x) * st.y * wv.y + bv.y;
    v.z = (v.z - st.x) * st.y * wv.z + bv.z;
    v.w = (v.w - st.x) * st.y * wv.w + bv.w;
    ((float4*)buf)[i] = v;
}

// ======================= softmax-pool =======================
__global__ __launch_bounds__(256) void pool_partial_big(const ushort* __restrict__ AW, const ushort* __restrict__ AU,
                                                        const float* __restrict__ X, const float2* __restrict__ stats,
                                                        const float* __restrict__ gnw, const float* __restrict__ gnb,
                                                        const float* __restrict__ g,
                                                        float* __restrict__ part, int rpb)
{
    const int s = blockIdx.x, ch = blockIdx.y, NC = gridDim.y, d = threadIdx.x;
    const long rowbase = ((long)s * NC + ch) * rpb;
    const float g0 = g[0];
    const float2 st = stats[s];
    const float wd = gnw[d], bd = gnb[d];
    float l = 0.f, acc = 0.f;
    for (int j = 0; j < rpb; ++j) {
        long idx = (rowbase + j) * DD + d;
        float aw = b2f(AW[idx]);
        float au = b2f(AU[idx]);
        float x = (X[idx] - st.x) * st.y * wd + bd;
        float a = g0 * tanhf(aw) * (1.f / (1.f + __expf(-au)));
        float e = __expf(a);
        l += e; acc += e * x;
    }
    long pbase = (long)(s * NC + ch) * 512;
    part[pbase + d] = l;
    part[pbase + 256 + d] = acc;
}

__global__ __launch_bounds__(256) void pool_partial_small(const float* __restrict__ AW, const float* __restrict__ AU,
                                                          const float* __restrict__ X, const float* __restrict__ g,
                                                          float* __restrict__ part, int rpb)
{
    const int s = blockIdx.x, d = threadIdx.x;
    const long rowbase = (long)s * rpb;
    const float g0 = g[0];
    float l = 0.f, acc = 0.f;
    for (int j = 0; j < rpb; ++j) {
        long idx = (rowbase + j) * DD + d;
        float a = g0 * tanhf(AW[idx]) * (1.f / (1.f + __expf(-AU[idx])));
        float e = __expf(a);
        l += e; acc += e * X[idx];
    }
    long pbase = (long)s * 512;
    part[pbase + d] = l;
    part[pbase + 256 + d] = acc;
}

__global__ __launch_bounds__(256) void pool_final(const float* __restrict__ part, float* __restrict__ out, int NC)
{
    const int s = blockIdx.x, d = threadIdx.x;
    float l = 0.f, acc = 0.f;
    for (int c = 0; c < NC; ++c) {
        long pbase = (long)(s * NC + c) * 512;
        l += part[pbase + d];
        acc += part[pbase + 256 + d];
    }
    out[(long)s * DD + d] = acc / l;
}

// ======================= BatchNorm + classifier =======================
__global__ __launch_bounds__(256) void bn_cls(const float* __restrict__ emb, const float* __restrict__ bn_w,
                                              const float* __restrict__ bn_b, const float* __restrict__ cls_W,
                                              const float* __restrict__ cls_b, float* __restrict__ out)
{
    int d = threadIdx.x;
    float e0 = emb[d], e1 = emb[256 + d], e2 = emb[512 + d], e3 = emb[768 + d];
    float mu = 0.25f * (e0 + e1 + e2 + e3);
    float v0 = e0 - mu, v1 = e1 - mu, v2 = e2 - mu, v3 = e3 - mu;
    float var = 0.25f * (v0*v0 + v1*v1 + v2*v2 + v3*v3);
    float rs = rsqrtf(var + 1e-5f);
    float w = bn_w[d], bb = bn_b[d];
    float z0 = v0*rs*w + bb, z1 = v1*rs*w + bb, z2 = v2*rs*w + bb, z3 = v3*rs*w + bb;
    float w0 = cls_W[d], w1 = cls_W[256 + d];
    __shared__ float red[8][256];
    red[0][d] = z0*w0; red[1][d] = z0*w1;
    red[2][d] = z1*w0; red[3][d] = z1*w1;
    red[4][d] = z2*w0; red[5][d] = z2*w1;
    red[6][d] = z3*w0; red[7][d] = z3*w1;
    __syncthreads();
    for (int off = 128; off > 0; off >>= 1) {
        if (d < off) {
            #pragma unroll
            for (int m = 0; m < 8; ++m) red[m][d] += red[m][d + off];
        }
        __syncthreads();
    }
    if (d < 8) out[d] = red[d][0] + cls_b[d & 1];
}

// ======================= host =======================
extern "C" void kernel_launch(void* const* d_in, const int* in_sizes, int n_in,
                              void* d_out, int out_size, void* d_ws, size_t ws_size,
                              hipStream_t stream)
{
    (void)in_sizes; (void)n_in; (void)out_size;
#define F(i) ((const float*)d_in[i])
    const float* bags = F(0);

    const size_t smallF = 1600000;
    int nch = 1;
    while (nch < 128) {
        size_t bigF_ = ((size_t)(128 / nch)) * 512 * 256;
        if ((3 * bigF_ + smallF) * 4 <= ws_size) break;
        nch <<= 1;
    }
    const int cseq = 128 / nch;
    const size_t crows = (size_t)cseq * 512;
    const size_t bigF = crows * 256;

    float* Xb  = (float*)d_ws;                 // attn output / gemm input (raw fp32)
    float* Qb  = Xb + bigF;                    // Q fp32
    float* KVb = Xb + 2 * bigF;                // K,V bf16 halves; later AW,AU bf16
    ushort* Kb = (ushort*)KVb;
    ushort* Vb = Kb + crows * 256;
    float* sm = Xb + 3 * bigF;
    ushort* Wbig = (ushort*)sm;                // 8 mats x 65536 shorts (frag order, bf16)
    ushort* Wsm  = Wbig + 8 * 65536;           // 5 mats x 131072 shorts (hi/lo row-major)
    float* after = sm + 262144 + 327680;
    float* local_ = after;                     // 128*256
    float* gq   = local_ + 32768;
    float* gkv  = gq + 32768;
    ushort* gkb = (ushort*)gkv;
    ushort* gvb = gkb + 32768;
    float* go   = gkv + 32768;
    float* AWg  = go + 32768;
    float* AUg  = AWg + 32768;
    float* embb = AUg + 32768;                 // 1024
    float* gnpart = embb + 1024;               // 256 floats
    float2* gnstats = (float2*)(gnpart + 256); // 128 x float2
    float* ppart = gnpart + 512;               // [1024][512] max

    // --- weight conversion ---
    WPtrs8 wb8; const int bigidx[8] = {1, 3, 5, 9, 11, 13, 25, 27};
    for (int i = 0; i < 8; ++i) wb8.w[i] = F(bigidx[i]);
    wcvt_frag<<<256, 256, 0, stream>>>(wb8, Wbig);
    WPtrs5 ws5; const int smidx[5] = {17, 19, 21, 30, 32};
    for (int i = 0; i < 5; ++i) ws5.w[i] = F(smidx[i]);
    wcvt_old<<<320, 256, 0, stream>>>(ws5, Wsm);
    gnzero<<<1, 256, 0, stream>>>(gnpart);

    dim3 blk(256);
    const int gx = (int)(crows / 128);
    const float invBig = 1.f / 131072.f;

    for (int c = 0; c < nch; ++c) {
        const float* xin = bags + (size_t)c * bigF;
        // retention 1
        GemmBig g1 = {xin, nullptr, nullptr, nullptr, Wbig,
                      F(2), F(4), F(6), Qb, Kb, Vb, 0b110};
        gemm_big<<<dim3(gx, 3), blk, 0, stream>>>(g1);
        attn<<<dim3(cseq, 8), blk, 0, stream>>>(Qb, Kb, Vb, Xb, gnpart);
        gn_final<<<1, blk, 0, stream>>>(gnpart, gnstats, cseq, invBig);
        // retention 2 (GN of layer1 fused into A-staging)
        GemmBig g2 = {Xb, gnstats, F(7), F(8), Wbig + 3 * 65536,
                      F(10), F(12), F(14), Qb, Kb, Vb, 0b110};
        gemm_big<<<dim3(gx, 3), blk, 0, stream>>>(g2);
        attn<<<dim3(cseq, 8), blk, 0, stream>>>(Qb, Kb, Vb, Xb, gnpart);
        gn_final<<<1, blk, 0, stream>>>(gnpart, gnstats, cseq, invBig);
        // local pool (GN of layer2 fused into A-staging; gates out bf16)
        GemmBig gp = {Xb, gnstats, F(15), F(16), Wbig + 6 * 65536,
                      F(26), F(28), nullptr, Kb, Vb, nullptr, 0b11};
        gemm_big<<<dim3(gx, 2), blk, 0, stream>>>(gp);
        pool_partial_big<<<dim3(cseq, 8), blk, 0, stream>>>(Kb, Vb, Xb, gnstats, F(15), F(16), F(29), ppart, 64);
        pool_final<<<cseq, blk, 0, stream>>>(ppart, local_ + (size_t)c * cseq * 256, 8);
    }

    // global retention on local [4 x 32 x 256] = 128 rows
    GemmPtrs gg = {local_, Wsm, Wsm + 131072, Wsm + 2 * 131072,
                   F(18), F(20), F(22), gq, gkb, gvb, 0b110};
    gemm_small<<<dim3(1, 3), blk, 0, stream>>>(gg);
    small_attn<<<32, 64, 0, stream>>>(gq, gkb, gvb, go);
    gn_stats<<<4, blk, 0, stream>>>(go, (float2*)gnpart, 32);
    gn_final<<<1, blk, 0, stream>>>(gnpart, gnstats, 4, 1.f / 8192.f);
    gn_apply<<<32, blk, 0, stream>>>(go, gnstats, F(23), F(24), 13);

    GemmPtrs gpg = {go, Wsm + 3 * 131072, Wsm + 4 * 131072, nullptr,
                    F(31), F(33), nullptr, AWg, AUg, nullptr, 0};
    gemm_small<<<dim3(1, 2), blk, 0, stream>>>(gpg);
    pool_partial_small<<<4, blk, 0, stream>>>(AWg, AUg, go, F(34), ppart, 32);
    pool_final<<<4, blk, 0, stream>>>(ppart, embb, 1);

    bn_cls<<<1, blk, 0, stream>>>(embb, F(35), F(36), F(37), F(38), (float*)d_out);
#undef F
}

// Round 5
// 656.731 us; speedup vs baseline: 3.5051x; 1.2131x over previous
//
#include <hip/hip_runtime.h>

typedef unsigned int uint;
typedef unsigned short ushort;
typedef __attribute__((ext_vector_type(8))) short short8;
typedef __attribute__((ext_vector_type(4))) float f32x4;

#define DD 256

__device__ __forceinline__ float b2f(ushort u) {
    return __uint_as_float(((uint)u) << 16);
}
__device__ __forceinline__ ushort f2b(float f) {
    uint u = __float_as_uint(f);
    u += 0x7FFFu + ((u >> 16) & 1u);
    return (ushort)(u >> 16);
}
__device__ __forceinline__ void split2(float x, short& h, short& l) {
    uint u = __float_as_uint(x);
    uint hr = (u + 0x7FFFu + ((u >> 16) & 1u)) & 0xFFFF0000u;
    h = (short)(hr >> 16);
    l = (short)(__float_as_uint(x - __uint_as_float(hr)) >> 16);
}
// scrambled bf16 layout (big path): element (r, c) of an [R][256] matrix lives at
//   t=r>>7, r7=r&127, w=((r7>>6)&1)|(((c>>7)&1)<<1), mt=(r7>>4)&3, quad=(r7>>2)&3, i=r7&3,
//   ct=(c>>4)&7, r16=c&15
//   addr = t*32768 + w*8192 + (mt*8+ct)*256 + (quad*16+r16)*4 + i
__device__ __forceinline__ size_t scramble4(int g0, int c) {   // i==0 base (rows g0..g0+3)
    int t = g0 >> 7, r7 = g0 & 127;
    int w_ = ((r7 >> 6) & 1) | (((c >> 7) & 1) << 1);
    int mt = (r7 >> 4) & 3, quad = (r7 >> 2) & 3;
    int ct = (c >> 4) & 7, r16 = c & 15;
    return (size_t)t * 32768 + w_ * 8192 + (mt * 8 + ct) * 256 + (quad * 16 + r16) * 4;
}

// ======================= weight pre-split, row-major hi/lo (small path, split3) =======================
struct WPtrs5 { const float* w[5]; };

__global__ __launch_bounds__(256) void wcvt_old(WPtrs5 p, ushort* __restrict__ out)
{
    int idx = blockIdx.x * 256 + threadIdx.x;
    int mat = idx >> 14;
    int off = idx & 16383;
    float4 v = *((const float4*)p.w[mat] + off);
    float xs[4] = {v.x, v.y, v.z, v.w};
    ushort h[4], l[4];
    #pragma unroll
    for (int i = 0; i < 4; ++i) {
        short hh, ll;
        split2(xs[i], hh, ll);
        h[i] = (ushort)hh; l[i] = (ushort)ll;
    }
    *((ushort4*)(out + (size_t)mat * 131072) + off) = make_ushort4(h[0], h[1], h[2], h[3]);
    *((ushort4*)(out + (size_t)mat * 131072 + 65536) + off) = make_ushort4(l[0], l[1], l[2], l[3]);
}

// ======================= weight bf16 round, MFMA-fragment order (big path) =======================
struct WPtrs8 { const float* w[8]; };

__global__ __launch_bounds__(256) void wcvt_frag(WPtrs8 p, ushort* __restrict__ out)
{
    int idx = blockIdx.x * 256 + threadIdx.x;    // short8 index; 8*8*16*64 = 65536 total
    int lane = idx & 63;
    int nt = (idx >> 6) & 15;
    int kc = (idx >> 10) & 7;
    int mat = idx >> 13;
    int n = nt * 16 + (lane & 15);
    int k = kc * 32 + (lane >> 4) * 8;
    const float* src = p.w[mat] + n * DD + k;
    float4 x0 = *(const float4*)src;
    float4 x1 = *(const float4*)(src + 4);
    float xs[8] = {x0.x, x0.y, x0.z, x0.w, x1.x, x1.y, x1.z, x1.w};
    short o8[8];
    #pragma unroll
    for (int i = 0; i < 8; ++i) o8[i] = (short)f2b(xs[i]);
    *(short8*)(out + (size_t)idx * 8) = (short8){o8[0],o8[1],o8[2],o8[3],o8[4],o8[5],o8[6],o8[7]};
}

// ======================= fused multi-mat MFMA GEMM: stage-A once, loop mats =======================
struct GemmFused {
    const float* X;            // raw rows [R][256] fp32
    const float2* stats;       // per-seq (mean, rsig) or nullptr
    const float* gnw; const float* gnb;
    const ushort* W;           // fragment-ordered bf16, mats consecutive (65536 shorts each)
    const float* b0; const float* b1; const float* b2;
    void* o0; void* o1; void* o2;
    int bf16mask;              // per-mat: 1 = scrambled bf16 out, 0 = row-major fp32 out
    int nmat;
};

__global__ __launch_bounds__(256, 2) void gemm_fused(GemmFused p)
{
    __shared__ __align__(16) ushort As[128][264];
    const int tid = threadIdx.x, w = tid >> 6, lane = tid & 63;
    const int quad = lane >> 4, r16 = lane & 15;
    const long row0 = (long)blockIdx.x * 128;
    const int wrow = (w & 1) * 64, wcol = (w >> 1) * 128;
    const bool gn = (p.stats != nullptr);

    float mu = 0.f, rsg = 1.f;
    if (gn) { float2 st = p.stats[row0 >> 9]; mu = st.x; rsg = st.y; }

    // ---- stage entire A tile to LDS (once): thread -> row=tid>>1, k-half=(tid&1)*128 ----
    {
        const int arow = tid >> 1;
        const int kh = (tid & 1) * 128;
        const float* src = p.X + (row0 + arow) * DD + kh;
        #pragma unroll
        for (int i = 0; i < 8; ++i) {
            float4 x0 = *(const float4*)(src + i * 16);
            float4 x1 = *(const float4*)(src + i * 16 + 4);
            float4 x2 = *(const float4*)(src + i * 16 + 8);
            float4 x3 = *(const float4*)(src + i * 16 + 12);
            float xs[16] = {x0.x,x0.y,x0.z,x0.w, x1.x,x1.y,x1.z,x1.w,
                            x2.x,x2.y,x2.z,x2.w, x3.x,x3.y,x3.z,x3.w};
            if (gn) {
                const float* gwp = p.gnw + kh + i * 16;
                const float* gbp = p.gnb + kh + i * 16;
                #pragma unroll
                for (int j = 0; j < 16; ++j)
                    xs[j] = (xs[j] - mu) * rsg * gwp[j] + gbp[j];
            }
            short o16[16];
            #pragma unroll
            for (int j = 0; j < 16; ++j) o16[j] = (short)f2b(xs[j]);
            *(short8*)&As[arow][kh + i * 16]     = (short8){o16[0],o16[1],o16[2],o16[3],o16[4],o16[5],o16[6],o16[7]};
            *(short8*)&As[arow][kh + i * 16 + 8] = (short8){o16[8],o16[9],o16[10],o16[11],o16[12],o16[13],o16[14],o16[15]};
        }
    }
    __syncthreads();     // the ONLY barrier

    const int nt0 = wcol >> 4;
    for (int m = 0; m < p.nmat; ++m) {
        const ushort* Wm = p.W + (size_t)m * 65536;
        const float* bias = (m == 0) ? p.b0 : (m == 1 ? p.b1 : p.b2);
        void* out = (m == 0) ? p.o0 : (m == 1 ? p.o1 : p.o2);
        const int isbf = (p.bf16mask >> m) & 1;

        f32x4 acc[4][8];
        #pragma unroll
        for (int mt = 0; mt < 4; ++mt)
            #pragma unroll
            for (int ct = 0; ct < 8; ++ct)
                acc[mt][ct] = (f32x4){0.f, 0.f, 0.f, 0.f};

        #pragma unroll 2
        for (int kc = 0; kc < 8; ++kc) {
            short8 bfr[8];
            #pragma unroll
            for (int ct = 0; ct < 8; ++ct)
                bfr[ct] = *(const short8*)(Wm + (((kc * 16 + nt0 + ct) << 9) + lane * 8));
            short8 af[4];
            #pragma unroll
            for (int mt = 0; mt < 4; ++mt)
                af[mt] = *(const short8*)&As[wrow + mt * 16 + r16][kc * 32 + quad * 8];
            #pragma unroll
            for (int ct = 0; ct < 8; ++ct)
                #pragma unroll
                for (int mt = 0; mt < 4; ++mt)
                    acc[mt][ct] = __builtin_amdgcn_mfma_f32_16x16x32_bf16(af[mt], bfr[ct], acc[mt][ct], 0, 0, 0);
        }

        if (isbf) {
            // scrambled bf16 store: per (mt,ct) one ushort4 per lane, 512B contiguous per instr
            ushort* o = (ushort*)out;
            const size_t base = (size_t)blockIdx.x * 32768 + (size_t)w * 8192 + (size_t)lane * 4;
            #pragma unroll
            for (int ct = 0; ct < 8; ++ct) {
                const float bv = bias[wcol + ct * 16 + r16];
                #pragma unroll
                for (int mt = 0; mt < 4; ++mt) {
                    f32x4 a = acc[mt][ct];
                    *(ushort4*)&o[base + (size_t)(mt * 8 + ct) * 256] =
                        make_ushort4(f2b(a[0]+bv), f2b(a[1]+bv), f2b(a[2]+bv), f2b(a[3]+bv));
                }
            }
        } else {
            float* o = (float*)out;
            #pragma unroll
            for (int ct = 0; ct < 8; ++ct) {
                const int col = wcol + ct * 16 + r16;
                const float bv = bias[col];
                #pragma unroll
                for (int mt = 0; mt < 4; ++mt) {
                    const long rb = row0 + wrow + mt * 16 + quad * 4;
                    f32x4 a = acc[mt][ct];
                    #pragma unroll
                    for (int i = 0; i < 4; ++i) o[(rb + i) * DD + col] = a[i] + bv;
                }
            }
        }
    }
}

// ======================= small MFMA GEMM (128-row global path; split3, proven) =======================
struct GemmPtrs {
    const float* X;
    const ushort* W0; const ushort* W1; const ushort* W2;
    const float* b0; const float* b1; const float* b2;
    void* o0; void* o1; void* o2;
    int bf16mask;
};

__global__ __launch_bounds__(256, 2) void gemm_small(GemmPtrs p)
{
    __shared__ __align__(16) short As[2][128][40];
    __shared__ __align__(16) short Bsm[2][256][40];
    const int tid = threadIdx.x;
    const int w = tid >> 6, lane = tid & 63;
    const int quad = lane >> 4, r16 = lane & 15;
    const long row0 = (long)blockIdx.x * 128;
    const int mat = blockIdx.y;
    const ushort* W = (mat == 0) ? p.W0 : (mat == 1 ? p.W1 : p.W2);
    const float* bias = (mat == 0) ? p.b0 : (mat == 1 ? p.b1 : p.b2);
    void* out = (mat == 0) ? p.o0 : (mat == 1 ? p.o1 : p.o2);
    const int isbf = (p.bf16mask >> mat) & 1;
    const int wrow = (w & 1) * 64;
    const int wcol = (w >> 1) * 128;

    f32x4 acc[4][8];
    #pragma unroll
    for (int rt = 0; rt < 4; ++rt)
        #pragma unroll
        for (int ct = 0; ct < 8; ++ct)
            acc[rt][ct] = (f32x4){0.f, 0.f, 0.f, 0.f};

    const int arow = tid >> 1;
    const int kb = (tid & 1) << 4;
    const float* abase = p.X + (row0 + arow) * DD + kb;
    const short* wb = (const short*)W + tid * DD;

    for (int kc = 0; kc < 8; ++kc) {
        __syncthreads();
        {
            const float* src = abase + kc * 32;
            #pragma unroll
            for (int gx = 0; gx < 2; ++gx) {
                float4 x0 = *(const float4*)(src + gx * 8);
                float4 x1 = *(const float4*)(src + gx * 8 + 4);
                float xs[8] = {x0.x, x0.y, x0.z, x0.w, x1.x, x1.y, x1.z, x1.w};
                short h[8], l[8];
                #pragma unroll
                for (int i = 0; i < 8; ++i) split2(xs[i], h[i], l[i]);
                *(short8*)&As[0][arow][kb + gx * 8] = (short8){h[0],h[1],h[2],h[3],h[4],h[5],h[6],h[7]};
                *(short8*)&As[1][arow][kb + gx * 8] = (short8){l[0],l[1],l[2],l[3],l[4],l[5],l[6],l[7]};
            }
        }
        {
            const short* srcH = wb + kc * 32;
            const short* srcL = srcH + 65536;
            #pragma unroll
            for (int gx = 0; gx < 4; ++gx) {
                *(short8*)&Bsm[0][tid][gx * 8] = *(const short8*)(srcH + gx * 8);
                *(short8*)&Bsm[1][tid][gx * 8] = *(const short8*)(srcL + gx * 8);
            }
        }
        __syncthreads();
        short8 af[4][2];
        #pragma unroll
        for (int rt = 0; rt < 4; ++rt) {
            const int rr = wrow + rt * 16 + r16;
            af[rt][0] = *(const short8*)&As[0][rr][quad * 8];
            af[rt][1] = *(const short8*)&As[1][rr][quad * 8];
        }
        #pragma unroll
        for (int ct = 0; ct < 8; ++ct) {
            const int cc = wcol + ct * 16 + r16;
            short8 bh = *(const short8*)&Bsm[0][cc][quad * 8];
            short8 bl = *(const short8*)&Bsm[1][cc][quad * 8];
            #pragma unroll
            for (int rt = 0; rt < 4; ++rt) {
                acc[rt][ct] = __builtin_amdgcn_mfma_f32_16x16x32_bf16(af[rt][0], bh, acc[rt][ct], 0, 0, 0);
                acc[rt][ct] = __builtin_amdgcn_mfma_f32_16x16x32_bf16(af[rt][0], bl, acc[rt][ct], 0, 0, 0);
                acc[rt][ct] = __builtin_amdgcn_mfma_f32_16x16x32_bf16(af[rt][1], bh, acc[rt][ct], 0, 0, 0);
            }
        }
    }
    #pragma unroll
    for (int ct = 0; ct < 8; ++ct) {
        const int col = wcol + ct * 16 + r16;
        const float bv = bias[col];
        #pragma unroll
        for (int rt = 0; rt < 4; ++rt) {
            const long rb = row0 + wrow + rt * 16 + quad * 4;
            f32x4 a = acc[rt][ct];
            if (isbf) {
                ushort* o = (ushort*)out;
                #pragma unroll
                for (int i = 0; i < 4; ++i) o[(rb + i) * DD + col] = f2b(a[i] + bv);
            } else {
                float* o = (float*)out;
                #pragma unroll
                for (int i = 0; i < 4; ++i) o[(rb + i) * DD + col] = a[i] + bv;
            }
        }
    }
}

// ======================= banded decay attention (K/V scrambled bf16) + fused GN stats =======================
__global__ __launch_bounds__(256) void attn(const float* __restrict__ Q, const ushort* __restrict__ K,
                                            const ushort* __restrict__ V, float* __restrict__ O,
                                            float* __restrict__ part)
{
    __shared__ __align__(16) float Kt[96][36];
    __shared__ __align__(16) float Vt[96][36];
    const int tid = threadIdx.x;
    const int rowIdx = tid >> 2;
    const int qq = tid & 3;
    const int t0 = blockIdx.y * 64;
    const long sbase = (long)blockIdx.x * 512;
    const int lrem = 512 - t0;
    const int ktrows = lrem < 96 ? lrem : 96;
    float sm = 0.f, ssum = 0.f;

    for (int h = 0; h < 8; ++h) {
        #pragma unroll
        for (int it = 0; it < 3; ++it) {
            int u = tid + it * 256;            // 768 units = 24 row-quads x 32 cols
            int d = u & 31, kr4 = u >> 5;
            if (kr4 * 4 < ktrows) {
                int g0 = (int)sbase + t0 + kr4 * 4;
                int c = h * 32 + d;
                size_t addr = scramble4(g0, c);
                ushort4 kv = *(const ushort4*)&K[addr];
                ushort4 vv = *(const ushort4*)&V[addr];
                int lr = kr4 * 4;
                Kt[lr+0][d] = b2f(kv.x); Kt[lr+1][d] = b2f(kv.y);
                Kt[lr+2][d] = b2f(kv.z); Kt[lr+3][d] = b2f(kv.w);
                Vt[lr+0][d] = b2f(vv.x); Vt[lr+1][d] = b2f(vv.y);
                Vt[lr+2][d] = b2f(vv.z); Vt[lr+3][d] = b2f(vv.w);
            }
        }
        __syncthreads();

        float qr[8];
        {
            long gq_ = (sbase + t0 + rowIdx) * DD + h * 32 + (qq << 3);
            float4 a = *(const float4*)&Q[gq_];
            float4 b = *(const float4*)&Q[gq_ + 4];
            qr[0] = a.x; qr[1] = a.y; qr[2] = a.z; qr[3] = a.w;
            qr[4] = b.x; qr[5] = b.y; qr[6] = b.z; qr[7] = b.w;
        }
        float o[8] = {0.f, 0.f, 0.f, 0.f, 0.f, 0.f, 0.f, 0.f};
        for (int dl = 0; dl < 32; ++dl) {
            int krow = rowIdx + dl;
            if (krow < ktrows) {
                const float* kp = &Kt[krow][qq << 3];
                float4 ka = *(const float4*)kp;
                float4 kb2 = *(const float4*)(kp + 4);
                float s = qr[0]*ka.x + qr[1]*ka.y + qr[2]*ka.z + qr[3]*ka.w
                        + qr[4]*kb2.x + qr[5]*kb2.y + qr[6]*kb2.z + qr[7]*kb2.w;
                s += __shfl_xor(s, 1, 64);
                s += __shfl_xor(s, 2, 64);
                s *= __expf(-(float)dl);
                const float* vp = &Vt[krow][qq << 3];
                float4 va = *(const float4*)vp;
                float4 vb = *(const float4*)(vp + 4);
                o[0] += s*va.x; o[1] += s*va.y; o[2] += s*va.z; o[3] += s*va.w;
                o[4] += s*vb.x; o[5] += s*vb.y; o[6] += s*vb.z; o[7] += s*vb.w;
            }
        }
        long go_ = (sbase + t0 + rowIdx) * DD + h * 32 + (qq << 3);
        *(float4*)&O[go_]     = make_float4(o[0], o[1], o[2], o[3]);
        *(float4*)&O[go_ + 4] = make_float4(o[4], o[5], o[6], o[7]);
        #pragma unroll
        for (int i = 0; i < 8; ++i) { sm += o[i]; ssum += o[i] * o[i]; }
        __syncthreads();
    }
    #pragma unroll
    for (int off = 32; off > 0; off >>= 1) {
        sm   += __shfl_down(sm, off, 64);
        ssum += __shfl_down(ssum, off, 64);
    }
    __shared__ float red2[8];
    const int wv = tid >> 6;
    if ((tid & 63) == 0) { red2[wv] = sm; red2[4 + wv] = ssum; }
    __syncthreads();
    if (tid == 0) atomicAdd(&part[2 * blockIdx.x],     red2[0] + red2[1] + red2[2] + red2[3]);
    if (tid == 1) atomicAdd(&part[2 * blockIdx.x + 1], red2[4] + red2[5] + red2[6] + red2[7]);
}

// ======================= small dense attention (N=32), row-major bf16 K/V =======================
__global__ __launch_bounds__(64) void small_attn(const float* __restrict__ Q, const ushort* __restrict__ K,
                                                 const ushort* __restrict__ V, float* __restrict__ O)
{
    int b = blockIdx.x >> 3, h = blockIdx.x & 7;
    int i = threadIdx.x;
    if (i >= 32) return;
    long base = (long)b * 32 * DD + h * 32;
    float qr[32], o[32];
    #pragma unroll
    for (int d4 = 0; d4 < 8; ++d4) {
        float4 t = *(const float4*)&Q[base + (long)i * DD + d4 * 4];
        qr[d4*4+0] = t.x; qr[d4*4+1] = t.y; qr[d4*4+2] = t.z; qr[d4*4+3] = t.w;
    }
    #pragma unroll
    for (int d = 0; d < 32; ++d) o[d] = 0.f;
    for (int j = i; j < 32; ++j) {
        float s = 0.f;
        #pragma unroll
        for (int d4 = 0; d4 < 8; ++d4) {
            ushort4 kv = *(const ushort4*)&K[base + (long)j * DD + d4 * 4];
            s += qr[d4*4+0]*b2f(kv.x) + qr[d4*4+1]*b2f(kv.y) + qr[d4*4+2]*b2f(kv.z) + qr[d4*4+3]*b2f(kv.w);
        }
        s *= __expf(-(float)(j - i));
        #pragma unroll
        for (int d4 = 0; d4 < 8; ++d4) {
            ushort4 vv = *(const ushort4*)&V[base + (long)j * DD + d4 * 4];
            o[d4*4+0] += s*b2f(vv.x); o[d4*4+1] += s*b2f(vv.y); o[d4*4+2] += s*b2f(vv.z); o[d4*4+3] += s*b2f(vv.w);
        }
    }
    #pragma unroll
    for (int d4 = 0; d4 < 8; ++d4)
        *(float4*)&O[base + (long)i * DD + d4 * 4] = make_float4(o[d4*4+0], o[d4*4+1], o[d4*4+2], o[d4*4+3]);
}

// ======================= GN helpers =======================
__global__ __launch_bounds__(256) void gnzero(float* __restrict__ part)
{
    part[threadIdx.x] = 0.f;
}

__global__ __launch_bounds__(256) void gn_stats(const float* __restrict__ buf, float2* __restrict__ part, int rpb)
{
    const int s = blockIdx.x;
    const long base = (long)s * rpb * DD;
    const float4* p = (const float4*)(buf + base);
    const int nf4 = rpb * 64;
    float sm = 0.f, ss = 0.f;
    for (int i = threadIdx.x; i < nf4; i += 256) {
        float4 v = p[i];
        sm += v.x + v.y + v.z + v.w;
        ss += v.x*v.x + v.y*v.y + v.z*v.z + v.w*v.w;
    }
    #pragma unroll
    for (int off = 32; off > 0; off >>= 1) {
        sm += __shfl_down(sm, off, 64);
        ss += __shfl_down(ss, off, 64);
    }
    __shared__ float rs[4], rss[4];
    if ((threadIdx.x & 63) == 0) { rs[threadIdx.x >> 6] = sm; rss[threadIdx.x >> 6] = ss; }
    __syncthreads();
    if (threadIdx.x == 0)
        part[s] = make_float2(rs[0]+rs[1]+rs[2]+rs[3], rss[0]+rss[1]+rss[2]+rss[3]);
}

__global__ __launch_bounds__(256) void gn_final(float* __restrict__ part, float2* __restrict__ stats,
                                                int ng, float invN)
{
    int t = threadIdx.x;
    if (t < ng) {
        float sm = part[2*t], ss = part[2*t+1];
        float mean = sm * invN;
        float var = ss * invN - mean * mean;
        stats[t] = make_float2(mean, rsqrtf(var + 1e-5f));
        part[2*t] = 0.f; part[2*t+1] = 0.f;
    }
}

__global__ __launch_bounds__(256) void gn_apply(float* __restrict__ buf, const float2* __restrict__ stats,
                                                const float* __restrict__ w, const float* __restrict__ b, int shift)
{
    long i = (long)blockIdx.x * 256 + threadIdx.x;
    long e = i * 4;
    int seq = (int)(e >> shift);
    int d0 = (int)(e & 255);
    float2 st = stats[seq];
    float4 v = ((const float4*)buf)[i];
    float4 wv = *(const float4*)&w[d0];
    float4 bv = *(const float4*)&b[d0];
    v.x = (v.x - st.x) * st.y * wv.x + bv.x;
    v.y = (v.y - st.x) * st.y * wv.y + bv.y;
    v.z = (v.z - st.x) * st.y * wv.z + bv.z;
    v.w = (v.w - st.x) * st.y * wv.w + bv.w;
    ((float4*)buf)[i] = v;
}

// ======================= softmax-pool =======================
// big path: scrambled bf16 gate pre-activations + raw X + fused GN
__global__ __launch_bounds__(256) void pool_partial_big(const ushort* __restrict__ AW, const ushort* __restrict__ AU,
                                                        const float* __restrict__ X, const float2* __restrict__ stats,
                                                        const float* __restrict__ gnw, const float* __restrict__ gnb,
                                                        const float* __restrict__ g,
                                                        float* __restrict__ part, int rpb)
{
    const int s = blockIdx.x, ch = blockIdx.y, NC = gridDim.y, d = threadIdx.x;
    const long rowbase = ((long)s * NC + ch) * rpb;
    const float g0s = g[0];
    const float2 st = stats[s];
    const float wd = gnw[d], bd = gnb[d];
    float l = 0.f, acc = 0.f;
    for (int jj = 0; jj < rpb; jj += 4) {
        size_t addr = scramble4((int)rowbase + jj, d);
        ushort4 awv = *(const ushort4*)&AW[addr];
        ushort4 auv = *(const ushort4*)&AU[addr];
        ushort aws[4] = {awv.x, awv.y, awv.z, awv.w};
        ushort aus[4] = {auv.x, auv.y, auv.z, auv.w};
        #pragma unroll
        for (int i = 0; i < 4; ++i) {
            long idx = (rowbase + jj + i) * DD + d;
            float aw = b2f(aws[i]);
            float au = b2f(aus[i]);
            float x = (X[idx] - st.x) * st.y * wd + bd;
            float a = g0s * tanhf(aw) * (1.f / (1.f + __expf(-au)));
            float e = __expf(a);
            l += e; acc += e * x;
        }
    }
    long pbase = (long)(s * NC + ch) * 512;
    part[pbase + d] = l;
    part[pbase + 256 + d] = acc;
}

__global__ __launch_bounds__(256) void pool_partial_small(const float* __restrict__ AW, const float* __restrict__ AU,
                                                          const float* __restrict__ X, const float* __restrict__ g,
                                                          float* __restrict__ part, int rpb)
{
    const int s = blockIdx.x, d = threadIdx.x;
    const long rowbase = (long)s * rpb;
    const float g0 = g[0];
    float l = 0.f, acc = 0.f;
    for (int j = 0; j < rpb; ++j) {
        long idx = (rowbase + j) * DD + d;
        float a = g0 * tanhf(AW[idx]) * (1.f / (1.f + __expf(-AU[idx])));
        float e = __expf(a);
        l += e; acc += e * X[idx];
    }
    long pbase = (long)s * 512;
    part[pbase + d] = l;
    part[pbase + 256 + d] = acc;
}

__global__ __launch_bounds__(256) void pool_final(const float* __restrict__ part, float* __restrict__ out, int NC)
{
    const int s = blockIdx.x, d = threadIdx.x;
    float l = 0.f, acc = 0.f;
    for (int c = 0; c < NC; ++c) {
        long pbase = (long)(s * NC + c) * 512;
        l += part[pbase + d];
        acc += part[pbase + 256 + d];
    }
    out[(long)s * DD + d] = acc / l;
}

// ======================= BatchNorm + classifier =======================
__global__ __launch_bounds__(256) void bn_cls(const float* __restrict__ emb, const float* __restrict__ bn_w,
                                              const float* __restrict__ bn_b, const float* __restrict__ cls_W,
                                              const float* __restrict__ cls_b, float* __restrict__ out)
{
    int d = threadIdx.x;
    float e0 = emb[d], e1 = emb[256 + d], e2 = emb[512 + d], e3 = emb[768 + d];
    float mu = 0.25f * (e0 + e1 + e2 + e3);
    float v0 = e0 - mu, v1 = e1 - mu, v2 = e2 - mu, v3 = e3 - mu;
    float var = 0.25f * (v0*v0 + v1*v1 + v2*v2 + v3*v3);
    float rs = rsqrtf(var + 1e-5f);
    float w = bn_w[d], bb = bn_b[d];
    float z0 = v0*rs*w + bb, z1 = v1*rs*w + bb, z2 = v2*rs*w + bb, z3 = v3*rs*w + bb;
    float w0 = cls_W[d], w1 = cls_W[256 + d];
    __shared__ float red[8][256];
    red[0][d] = z0*w0; red[1][d] = z0*w1;
    red[2][d] = z1*w0; red[3][d] = z1*w1;
    red[4][d] = z2*w0; red[5][d] = z2*w1;
    red[6][d] = z3*w0; red[7][d] = z3*w1;
    __syncthreads();
    for (int off = 128; off > 0; off >>= 1) {
        if (d < off) {
            #pragma unroll
            for (int m = 0; m < 8; ++m) red[m][d] += red[m][d + off];
        }
        __syncthreads();
    }
    if (d < 8) out[d] = red[d][0] + cls_b[d & 1];
}

// ======================= host =======================
extern "C" void kernel_launch(void* const* d_in, const int* in_sizes, int n_in,
                              void* d_out, int out_size, void* d_ws, size_t ws_size,
                              hipStream_t stream)
{
    (void)in_sizes; (void)n_in; (void)out_size;
#define F(i) ((const float*)d_in[i])
    const float* bags = F(0);

    const size_t smallF = 1600000;
    int nch = 1;
    while (nch < 128) {
        size_t bigF_ = ((size_t)(128 / nch)) * 512 * 256;
        if ((3 * bigF_ + smallF) * 4 <= ws_size) break;
        nch <<= 1;
    }
    const int cseq = 128 / nch;
    const size_t crows = (size_t)cseq * 512;
    const size_t bigF = crows * 256;

    float* Xb  = (float*)d_ws;                 // attn output / gemm input (raw fp32)
    float* Qb  = Xb + bigF;                    // Q fp32
    float* KVb = Xb + 2 * bigF;                // K,V scrambled bf16 halves; later AW,AU
    ushort* Kb = (ushort*)KVb;
    ushort* Vb = Kb + crows * 256;
    float* sm = Xb + 3 * bigF;
    ushort* Wbig = (ushort*)sm;                // 8 mats x 65536 shorts (frag order, bf16)
    ushort* Wsm  = Wbig + 8 * 65536;           // 5 mats x 131072 shorts (hi/lo row-major)
    float* after = sm + 262144 + 327680;
    float* local_ = after;                     // 128*256
    float* gq   = local_ + 32768;
    float* gkv  = gq + 32768;
    ushort* gkb = (ushort*)gkv;
    ushort* gvb = gkb + 32768;
    float* go   = gkv + 32768;
    float* AWg  = go + 32768;
    float* AUg  = AWg + 32768;
    float* embb = AUg + 32768;                 // 1024
    float* gnpart = embb + 1024;               // 256 floats
    float2* gnstats = (float2*)(gnpart + 256); // 128 x float2
    float* ppart = gnpart + 512;               // [1024][512] max

    // --- weight conversion ---
    WPtrs8 wb8; const int bigidx[8] = {1, 3, 5, 9, 11, 13, 25, 27};
    for (int i = 0; i < 8; ++i) wb8.w[i] = F(bigidx[i]);
    wcvt_frag<<<256, 256, 0, stream>>>(wb8, Wbig);
    WPtrs5 ws5; const int smidx[5] = {17, 19, 21, 30, 32};
    for (int i = 0; i < 5; ++i) ws5.w[i] = F(smidx[i]);
    wcvt_old<<<320, 256, 0, stream>>>(ws5, Wsm);
    gnzero<<<1, 256, 0, stream>>>(gnpart);

    dim3 blk(256);
    const int gx = (int)(crows / 128);
    const float invBig = 1.f / 131072.f;

    for (int c = 0; c < nch; ++c) {
        const float* xin = bags + (size_t)c * bigF;
        // retention 1 (Q fp32 row-major, K/V scrambled bf16)
        GemmFused g1 = {xin, nullptr, nullptr, nullptr, Wbig,
                        F(2), F(4), F(6), Qb, Kb, Vb, 0b110, 3};
        gemm_fused<<<gx, blk, 0, stream>>>(g1);
        attn<<<dim3(cseq, 8), blk, 0, stream>>>(Qb, Kb, Vb, Xb, gnpart);
        gn_final<<<1, blk, 0, stream>>>(gnpart, gnstats, cseq, invBig);
        // retention 2 (GN of layer1 fused into A-staging)
        GemmFused g2 = {Xb, gnstats, F(7), F(8), Wbig + 3 * 65536,
                        F(10), F(12), F(14), Qb, Kb, Vb, 0b110, 3};
        gemm_fused<<<gx, blk, 0, stream>>>(g2);
        attn<<<dim3(cseq, 8), blk, 0, stream>>>(Qb, Kb, Vb, Xb, gnpart);
        gn_final<<<1, blk, 0, stream>>>(gnpart, gnstats, cseq, invBig);
        // local pool (GN of layer2 fused; gates out scrambled bf16)
        GemmFused gp = {Xb, gnstats, F(15), F(16), Wbig + 6 * 65536,
                        F(26), F(28), nullptr, Kb, Vb, nullptr, 0b11, 2};
        gemm_fused<<<gx, blk, 0, stream>>>(gp);
        pool_partial_big<<<dim3(cseq, 8), blk, 0, stream>>>(Kb, Vb, Xb, gnstats, F(15), F(16), F(29), ppart, 64);
        pool_final<<<cseq, blk, 0, stream>>>(ppart, local_ + (size_t)c * cseq * 256, 8);
    }

    // global retention on local [4 x 32 x 256] = 128 rows
    GemmPtrs gg = {local_, Wsm, Wsm + 131072, Wsm + 2 * 131072,
                   F(18), F(20), F(22), gq, gkb, gvb, 0b110};
    gemm_small<<<dim3(1, 3), blk, 0, stream>>>(gg);
    small_attn<<<32, 64, 0, stream>>>(gq, gkb, gvb, go);
    gn_stats<<<4, blk, 0, stream>>>(go, (float2*)gnpart, 32);
    gn_final<<<1, blk, 0, stream>>>(gnpart, gnstats, 4, 1.f / 8192.f);
    gn_apply<<<32, blk, 0, stream>>>(go, gnstats, F(23), F(24), 13);

    GemmPtrs gpg = {go, Wsm + 3 * 131072, Wsm + 4 * 131072, nullptr,
                    F(31), F(33), nullptr, AWg, AUg, nullptr, 0};
    gemm_small<<<dim3(1, 2), blk, 0, stream>>>(gpg);
    pool_partial_small<<<4, blk, 0, stream>>>(AWg, AUg, go, F(34), ppart, 32);
    pool_final<<<4, blk, 0, stream>>>(ppart, embb, 1);

    bn_cls<<<1, blk, 0, stream>>>(embb, F(35), F(36), F(37), F(38), (float*)d_out);
#undef F
}